// Round 1
// baseline (681.060 us; speedup 1.0000x reference)
//
#include <hip/hip_runtime.h>

// multihead self-attention: B=4 S=2048 D=1024 H=16 DK=64, causal, RoPE(theta=1e4)
// Pipeline (all bf16 MFMA internally, f32 softmax/accum):
//   cvt x,wq,wk,wv,wo -> bf16 | Q/K/V = x*W^T (mfma gemm) | rope(Q,K) |
//   flash attention -> Ob bf16 | out = Ob*wo^T (f32 out)

#define D_MODEL 1024
#define NH      16
#define DKH     64
#define SEQ     2048
#define BATCH   4
#define M_ROWS  (BATCH * SEQ)   // 8192

typedef __bf16 bf16x8 __attribute__((ext_vector_type(8)));
typedef float  f32x4  __attribute__((ext_vector_type(4)));
typedef unsigned short u16;
typedef unsigned int   u32;

__device__ __forceinline__ u16 f2bf(float f) {
  u32 u = __float_as_uint(f);
  u = (u + 0x7fffu + ((u >> 16) & 1u)) >> 16;   // RNE
  return (u16)u;
}
__device__ __forceinline__ float bf2f(u16 h) {
  return __uint_as_float(((u32)h) << 16);
}

// ---------------- f32 -> bf16 convert ----------------
__global__ void cvt_f32_bf16(const float* __restrict__ in, u16* __restrict__ out, int n) {
  int i = (blockIdx.x * blockDim.x + threadIdx.x) * 4;
  if (i >= n) return;
  float4 v = *(const float4*)(in + i);
  uint2 o;
  o.x = (u32)f2bf(v.x) | ((u32)f2bf(v.y) << 16);
  o.y = (u32)f2bf(v.z) | ((u32)f2bf(v.w) << 16);
  *(uint2*)(out + i) = o;
}

// ---------------- GEMM: C[M,N] = A[M,K] * W[N,K]^T  (bf16 in, bf16 or f32 out) ----
// 128x128 tile, BK=64, 256 threads (4 waves, 2x2 of 64x64), 16x16x32 bf16 mfma.
// LDS rows padded 64->72 elems (144B stride): 16B-aligned rows, 2-way bank aliasing (free).
template<int OUT_BF16>
__global__ __launch_bounds__(256) void gemm_bt(const u16* __restrict__ A,
                                               const u16* __restrict__ W,
                                               void* __restrict__ Cv,
                                               int M, int N, int K) {
  __shared__ u16 As[128][72];
  __shared__ u16 Bs[128][72];
  const int tid  = threadIdx.x;
  const int m0   = blockIdx.y * 128;
  const int n0   = blockIdx.x * 128;
  const int wave = tid >> 6, lane = tid & 63;
  const int quad = lane >> 4, l16 = lane & 15;
  const int wm = (wave >> 1) * 64, wn = (wave & 1) * 64;

  f32x4 acc[4][4];
#pragma unroll
  for (int i = 0; i < 4; ++i)
#pragma unroll
    for (int j = 0; j < 4; ++j) acc[i][j] = (f32x4){0.f, 0.f, 0.f, 0.f};

  for (int k0 = 0; k0 < K; k0 += 64) {
#pragma unroll
    for (int i = 0; i < 4; ++i) {           // stage 128x64 of A and W
      int c = tid + i * 256;
      int row = c >> 3, co = (c & 7) * 8;
      *(uint4*)&As[row][co] = *(const uint4*)(A + (size_t)(m0 + row) * K + k0 + co);
      *(uint4*)&Bs[row][co] = *(const uint4*)(W + (size_t)(n0 + row) * K + k0 + co);
    }
    __syncthreads();
#pragma unroll
    for (int kk = 0; kk < 64; kk += 32) {
      bf16x8 af[4], bf[4];
#pragma unroll
      for (int mi = 0; mi < 4; ++mi)
        af[mi] = *(const bf16x8*)&As[wm + mi * 16 + l16][kk + quad * 8];
#pragma unroll
      for (int ni = 0; ni < 4; ++ni)
        bf[ni] = *(const bf16x8*)&Bs[wn + ni * 16 + l16][kk + quad * 8];
#pragma unroll
      for (int mi = 0; mi < 4; ++mi)
#pragma unroll
        for (int ni = 0; ni < 4; ++ni)
          acc[mi][ni] = __builtin_amdgcn_mfma_f32_16x16x32_bf16(af[mi], bf[ni], acc[mi][ni], 0, 0, 0);
    }
    __syncthreads();
  }

  // epilogue: C layout col=lane&15, row=quad*4+reg
#pragma unroll
  for (int mi = 0; mi < 4; ++mi)
#pragma unroll
    for (int ni = 0; ni < 4; ++ni)
#pragma unroll
      for (int r = 0; r < 4; ++r) {
        int row = m0 + wm + mi * 16 + quad * 4 + r;
        int col = n0 + wn + ni * 16 + l16;
        if (OUT_BF16)
          ((u16*)Cv)[(size_t)row * N + col] = f2bf(acc[mi][ni][r]);
        else
          ((float*)Cv)[(size_t)row * N + col] = acc[mi][ni][r];
      }
}

// ---------------- RoPE in-place on bf16 Q and K ----------------
// pair p: elements (2p, 2p+1); i = p%32 (pair idx in head), s = (p/512)%2048
__global__ void rope_kernel(u16* __restrict__ Q, u16* __restrict__ Kb,
                            const int* __restrict__ pos, int npairs) {
  int p = blockIdx.x * blockDim.x + threadIdx.x;
  if (p >= npairs) return;
  int i = p & 31;
  int s = (p >> 9) & (SEQ - 1);
  float inv = expf((float)i * -0.28782313662425574f);  // ln(1e4)/32
  float ang = (float)pos[s] * inv;
  float c = cosf(ang), sn = sinf(ang);

  u32 qp = *(u32*)(Q + 2 * (size_t)p);
  float qe = bf2f((u16)(qp & 0xffff)), qo = bf2f((u16)(qp >> 16));
  float nqe = qe * c - qo * sn, nqo = qe * sn + qo * c;
  *(u32*)(Q + 2 * (size_t)p) = (u32)f2bf(nqe) | ((u32)f2bf(nqo) << 16);

  u32 kp = *(u32*)(Kb + 2 * (size_t)p);
  float ke = bf2f((u16)(kp & 0xffff)), ko = bf2f((u16)(kp >> 16));
  float nke = ke * c - ko * sn, nko = ke * sn + ko * c;
  *(u32*)(Kb + 2 * (size_t)p) = (u32)f2bf(nke) | ((u32)f2bf(nko) << 16);
}

// ---------------- causal flash attention ----------------
// grid (S/64, B*H); block 256 = 4 waves, each wave owns 16 q-rows.
// K-tiles of 32 keys. QK^T and PV via 16x16x32 bf16 mfma; online softmax f32.
__global__ __launch_bounds__(256) void flash_attn(const u16* __restrict__ Q,
                                                  const u16* __restrict__ Kg,
                                                  const u16* __restrict__ Vg,
                                                  u16* __restrict__ O) {
  __shared__ u16 Ks[32][72];       // [key][dk]  (B-frag for QK^T: contiguous dk)
  __shared__ u16 Vs[64][40];       // [dk][key]  (B-frag for PV: contiguous key)
  __shared__ u16 Ps[4][16][40];    // per-wave P 16x32 (A-operand layout)

  const int tid  = threadIdx.x;
  const int q0   = blockIdx.x * 64;
  const int bh   = blockIdx.y;
  const int b    = bh >> 4, h = bh & 15;
  const int wave = tid >> 6, lane = tid & 63;
  const int quad = lane >> 4, l16 = lane & 15;

  // load this wave's Q fragments (16 rows x 64 dk -> 2 k-chunks)
  bf16x8 qf[2];
  {
    int s = q0 + wave * 16 + l16;
    const u16* qp = Q + ((size_t)(b * SEQ + s)) * D_MODEL + h * DKH + quad * 8;
    qf[0] = *(const bf16x8*)(qp);
    qf[1] = *(const bf16x8*)(qp + 32);
  }

  f32x4 o[4];
#pragma unroll
  for (int d = 0; d < 4; ++d) o[d] = (f32x4){0.f, 0.f, 0.f, 0.f};
  float m[4] = {-__builtin_inff(), -__builtin_inff(), -__builtin_inff(), -__builtin_inff()};
  float l[4] = {0.f, 0.f, 0.f, 0.f};

  const int nkt = (q0 >> 5) + 2;   // key tiles covering [0, q0+64)
  for (int t = 0; t < nkt; ++t) {
    const int kt = t * 32;
    {   // stage K (row-major) and V (transposed)
      int key = tid >> 3, co = (tid & 7) * 8;
      const size_t src = ((size_t)(b * SEQ + kt + key)) * D_MODEL + h * DKH + co;
      *(uint4*)&Ks[key][co] = *(const uint4*)(Kg + src);
      union { uint4 u; u16 s[8]; } vv;
      vv.u = *(const uint4*)(Vg + src);
#pragma unroll
      for (int j = 0; j < 8; ++j) Vs[co + j][key] = vv.s[j];
    }
    __syncthreads();

    // S = Q K^T  (two 16-key n-tiles)
    f32x4 sc[2];
#pragma unroll
    for (int nt = 0; nt < 2; ++nt) {
      bf16x8 b0 = *(const bf16x8*)&Ks[nt * 16 + l16][quad * 8];
      bf16x8 b1 = *(const bf16x8*)&Ks[nt * 16 + l16][32 + quad * 8];
      f32x4 c = (f32x4){0.f, 0.f, 0.f, 0.f};
      c = __builtin_amdgcn_mfma_f32_16x16x32_bf16(qf[0], b0, c, 0, 0, 0);
      c = __builtin_amdgcn_mfma_f32_16x16x32_bf16(qf[1], b1, c, 0, 0, 0);
      sc[nt] = c;
    }

    // scale + causal mask (C layout: row=quad*4+r, col=l16)
    const int qrow = q0 + wave * 16 + quad * 4;
#pragma unroll
    for (int nt = 0; nt < 2; ++nt)
#pragma unroll
      for (int r = 0; r < 4; ++r) {
        int key = kt + nt * 16 + l16;
        float v = sc[nt][r] * 0.125f;
        sc[nt][r] = (key <= qrow + r) ? v : -__builtin_inff();
      }

    // online softmax per row (cols live in the 16 lanes of this quad)
#pragma unroll
    for (int r = 0; r < 4; ++r) {
      float mr = fmaxf(sc[0][r], sc[1][r]);
      mr = fmaxf(mr, __shfl_xor(mr, 1));
      mr = fmaxf(mr, __shfl_xor(mr, 2));
      mr = fmaxf(mr, __shfl_xor(mr, 4));
      mr = fmaxf(mr, __shfl_xor(mr, 8));
      float mnew  = fmaxf(m[r], mr);
      float alpha = expf(m[r] - mnew);           // first tile: exp(-inf)=0
      float p0 = expf(sc[0][r] - mnew);
      float p1 = expf(sc[1][r] - mnew);
      float rs = p0 + p1;
      rs += __shfl_xor(rs, 1);
      rs += __shfl_xor(rs, 2);
      rs += __shfl_xor(rs, 4);
      rs += __shfl_xor(rs, 8);
      l[r] = alpha * l[r] + rs;
      m[r] = mnew;
#pragma unroll
      for (int d = 0; d < 4; ++d) o[d][r] *= alpha;
      Ps[wave][quad * 4 + r][l16]      = f2bf(p0);
      Ps[wave][quad * 4 + r][16 + l16] = f2bf(p1);
    }
    __syncthreads();

    // O += P V   (P: A-operand from LDS; V: B-operand, k=key)
    bf16x8 pf = *(const bf16x8*)&Ps[wave][l16][quad * 8];
#pragma unroll
    for (int d = 0; d < 4; ++d) {
      bf16x8 vf = *(const bf16x8*)&Vs[d * 16 + l16][quad * 8];
      o[d] = __builtin_amdgcn_mfma_f32_16x16x32_bf16(pf, vf, o[d], 0, 0, 0);
    }
    __syncthreads();
  }

  // normalize and store
#pragma unroll
  for (int d = 0; d < 4; ++d)
#pragma unroll
    for (int r = 0; r < 4; ++r) {
      int s = q0 + wave * 16 + quad * 4 + r;
      O[((size_t)(b * SEQ + s)) * D_MODEL + h * DKH + d * 16 + l16] = f2bf(o[d][r] / l[r]);
    }
}

// ---------------- launch ----------------
extern "C" void kernel_launch(void* const* d_in, const int* in_sizes, int n_in,
                              void* d_out, int out_size, void* d_ws, size_t ws_size,
                              hipStream_t stream) {
  const float* x      = (const float*)d_in[0];
  const int*   tokpos = (const int*)d_in[1];
  const float* wq     = (const float*)d_in[2];
  const float* wk     = (const float*)d_in[3];
  const float* wv     = (const float*)d_in[4];
  const float* wo     = (const float*)d_in[5];
  float* out = (float*)d_out;

  char* ws = (char*)d_ws;
  // workspace layout (bytes); ~75.5 MB total. Ob reuses Xb (x dead after V proj).
  u16* Xb  = (u16*)(ws + 0);           // 16,777,216 B   (also Ob)
  u16* Wqb = (u16*)(ws + 16777216);    //  2,097,152 B
  u16* Wkb = (u16*)(ws + 18874368);
  u16* Wvb = (u16*)(ws + 20971520);
  u16* Wob = (u16*)(ws + 23068672);
  u16* Qb  = (u16*)(ws + 25165824);    // 16,777,216 B
  u16* Kb  = (u16*)(ws + 41943040);
  u16* Vb  = (u16*)(ws + 58720256);
  u16* Ob  = Xb;

  const int nX = BATCH * SEQ * D_MODEL;        // 8,388,608
  const int nW = D_MODEL * D_MODEL;            // 1,048,576

  cvt_f32_bf16<<<nX / 1024, 256, 0, stream>>>(x,  Xb,  nX);
  cvt_f32_bf16<<<nW / 1024, 256, 0, stream>>>(wq, Wqb, nW);
  cvt_f32_bf16<<<nW / 1024, 256, 0, stream>>>(wk, Wkb, nW);
  cvt_f32_bf16<<<nW / 1024, 256, 0, stream>>>(wv, Wvb, nW);
  cvt_f32_bf16<<<nW / 1024, 256, 0, stream>>>(wo, Wob, nW);

  dim3 gg(D_MODEL / 128, M_ROWS / 128);        // (8, 64)
  gemm_bt<1><<<gg, 256, 0, stream>>>(Xb, Wqb, Qb, M_ROWS, D_MODEL, D_MODEL);
  gemm_bt<1><<<gg, 256, 0, stream>>>(Xb, Wkb, Kb, M_ROWS, D_MODEL, D_MODEL);
  gemm_bt<1><<<gg, 256, 0, stream>>>(Xb, Wvb, Vb, M_ROWS, D_MODEL, D_MODEL);

  rope_kernel<<<(BATCH * SEQ * (D_MODEL / 2)) / 256, 256, 0, stream>>>(
      Qb, Kb, tokpos, BATCH * SEQ * (D_MODEL / 2));

  flash_attn<<<dim3(SEQ / 64, BATCH * NH), 256, 0, stream>>>(Qb, Kb, Vb, Ob);

  gemm_bt<0><<<gg, 256, 0, stream>>>(Ob, Wob, out, M_ROWS, D_MODEL, D_MODEL);
}

// Round 2
// 447.961 us; speedup vs baseline: 1.5204x; 1.5204x over previous
//
#include <hip/hip_runtime.h>

// multihead self-attention: B=4 S=2048 D=1024 H=16 DK=64, causal, RoPE(theta=1e4)
// Pipeline (all bf16 MFMA internally, f32 softmax/accum):
//   cvt x,wq,wk,wv,wo -> bf16 | Q/K/V = x*W^T (mfma gemm) | rope(Q,K) |
//   flash attention -> Ob bf16 | out = Ob*wo^T (f32 out)

#define D_MODEL 1024
#define NH      16
#define DKH     64
#define SEQ     2048
#define BATCH   4
#define M_ROWS  (BATCH * SEQ)   // 8192

typedef __bf16 bf16x8 __attribute__((ext_vector_type(8)));
typedef float  f32x4  __attribute__((ext_vector_type(4)));
typedef unsigned short u16;
typedef unsigned int   u32;

__device__ __forceinline__ u16 f2bf(float f) {
  u32 u = __float_as_uint(f);
  u = (u + 0x7fffu + ((u >> 16) & 1u)) >> 16;   // RNE
  return (u16)u;
}
__device__ __forceinline__ float bf2f(u16 h) {
  return __uint_as_float(((u32)h) << 16);
}

// ---------------- f32 -> bf16 convert ----------------
__global__ void cvt_f32_bf16(const float* __restrict__ in, u16* __restrict__ out, int n) {
  int i = (blockIdx.x * blockDim.x + threadIdx.x) * 4;
  if (i >= n) return;
  float4 v = *(const float4*)(in + i);
  uint2 o;
  o.x = (u32)f2bf(v.x) | ((u32)f2bf(v.y) << 16);
  o.y = (u32)f2bf(v.z) | ((u32)f2bf(v.w) << 16);
  *(uint2*)(out + i) = o;
}

// ---------------- GEMM: C[M,N] = A[M,K] * W[N,K]^T  (bf16 in, bf16 or f32 out) ----
// 128x128 tile, BK=64, 256 threads (4 waves, 2x2 of 64x64), 16x16x32 bf16 mfma.
template<int OUT_BF16>
__global__ __launch_bounds__(256) void gemm_bt(const u16* __restrict__ A,
                                               const u16* __restrict__ W,
                                               void* __restrict__ Cv,
                                               int M, int N, int K) {
  __shared__ u16 As[128][72];
  __shared__ u16 Bs[128][72];
  const int tid  = threadIdx.x;
  const int m0   = blockIdx.y * 128;
  const int n0   = blockIdx.x * 128;
  const int wave = tid >> 6, lane = tid & 63;
  const int quad = lane >> 4, l16 = lane & 15;
  const int wm = (wave >> 1) * 64, wn = (wave & 1) * 64;

  f32x4 acc[4][4];
#pragma unroll
  for (int i = 0; i < 4; ++i)
#pragma unroll
    for (int j = 0; j < 4; ++j) acc[i][j] = (f32x4){0.f, 0.f, 0.f, 0.f};

  for (int k0 = 0; k0 < K; k0 += 64) {
#pragma unroll
    for (int i = 0; i < 4; ++i) {           // stage 128x64 of A and W
      int c = tid + i * 256;
      int row = c >> 3, co = (c & 7) * 8;
      *(uint4*)&As[row][co] = *(const uint4*)(A + (size_t)(m0 + row) * K + k0 + co);
      *(uint4*)&Bs[row][co] = *(const uint4*)(W + (size_t)(n0 + row) * K + k0 + co);
    }
    __syncthreads();
#pragma unroll
    for (int kk = 0; kk < 64; kk += 32) {
      bf16x8 af[4], bf[4];
#pragma unroll
      for (int mi = 0; mi < 4; ++mi)
        af[mi] = *(const bf16x8*)&As[wm + mi * 16 + l16][kk + quad * 8];
#pragma unroll
      for (int ni = 0; ni < 4; ++ni)
        bf[ni] = *(const bf16x8*)&Bs[wn + ni * 16 + l16][kk + quad * 8];
#pragma unroll
      for (int mi = 0; mi < 4; ++mi)
#pragma unroll
        for (int ni = 0; ni < 4; ++ni)
          acc[mi][ni] = __builtin_amdgcn_mfma_f32_16x16x32_bf16(af[mi], bf[ni], acc[mi][ni], 0, 0, 0);
    }
    __syncthreads();
  }

  // epilogue: C layout col=lane&15, row=quad*4+reg
#pragma unroll
  for (int mi = 0; mi < 4; ++mi)
#pragma unroll
    for (int ni = 0; ni < 4; ++ni)
#pragma unroll
      for (int r = 0; r < 4; ++r) {
        int row = m0 + wm + mi * 16 + quad * 4 + r;
        int col = n0 + wn + ni * 16 + l16;
        if (OUT_BF16)
          ((u16*)Cv)[(size_t)row * N + col] = f2bf(acc[mi][ni][r]);
        else
          ((float*)Cv)[(size_t)row * N + col] = acc[mi][ni][r];
      }
}

// ---------------- RoPE in-place on bf16 Q and K ----------------
__global__ void rope_kernel(u16* __restrict__ Q, u16* __restrict__ Kb,
                            const int* __restrict__ pos, int npairs) {
  int p = blockIdx.x * blockDim.x + threadIdx.x;
  if (p >= npairs) return;
  int i = p & 31;
  int s = (p >> 9) & (SEQ - 1);
  float inv = expf((float)i * -0.28782313662425574f);  // ln(1e4)/32
  float ang = (float)pos[s] * inv;
  float c = cosf(ang), sn = sinf(ang);

  u32 qp = *(u32*)(Q + 2 * (size_t)p);
  float qe = bf2f((u16)(qp & 0xffff)), qo = bf2f((u16)(qp >> 16));
  float nqe = qe * c - qo * sn, nqo = qe * sn + qo * c;
  *(u32*)(Q + 2 * (size_t)p) = (u32)f2bf(nqe) | ((u32)f2bf(nqo) << 16);

  u32 kp = *(u32*)(Kb + 2 * (size_t)p);
  float ke = bf2f((u16)(kp & 0xffff)), ko = bf2f((u16)(kp >> 16));
  float nke = ke * c - ko * sn, nko = ke * sn + ko * c;
  *(u32*)(Kb + 2 * (size_t)p) = (u32)f2bf(nke) | ((u32)f2bf(nko) << 16);
}

// ---------------- causal flash attention ----------------
// grid (S/128, B*H), longest-first; block 256 = 4 waves, wave owns 32 q-rows (2 m-tiles).
// 64-key tiles. QK^T and PV via 16x16x32 bf16 mfma; log2-domain online softmax.
// LDS: Ks[key][dk] pad 72 (b128-aligned frags); Vs[dk][key] pad 68, stored as
// key-pair u32 (2-way banks = free), read as 2x ds_read_b64; Ps per-wave (no barrier).
#define SCALE_LOG2 0.180336875461f   // (1/sqrt(64)) * log2(e)
#define NEG_INF    (-__builtin_inff())

__global__ __launch_bounds__(256) void flash_attn(const u16* __restrict__ Q,
                                                  const u16* __restrict__ Kg,
                                                  const u16* __restrict__ Vg,
                                                  u16* __restrict__ O) {
  __shared__ u16 Ks[64][72];       // [key][dk]
  __shared__ u16 Vs[64][68];       // [dk][key]
  __shared__ u16 Ps[4][32][72];    // per-wave P 32x64 (A-operand layout)

  const int tid  = threadIdx.x;
  const int qblk = gridDim.x - 1 - blockIdx.x;   // longest blocks first
  const int q0   = qblk * 128;
  const int bh   = blockIdx.y;
  const int b    = bh >> 4, h = bh & 15;
  const int wave = tid >> 6, lane = tid & 63;
  const int quad = lane >> 4, l16 = lane & 15;

  // Q fragments for this wave: 2 m-tiles x 2 k-chunks
  bf16x8 qf[2][2];
#pragma unroll
  for (int mi = 0; mi < 2; ++mi) {
    int s = q0 + wave * 32 + mi * 16 + l16;
    const u16* qp = Q + ((size_t)(b * SEQ + s)) * D_MODEL + h * DKH + quad * 8;
    qf[mi][0] = *(const bf16x8*)(qp);
    qf[mi][1] = *(const bf16x8*)(qp + 32);
  }

  f32x4 o[2][4];
#pragma unroll
  for (int mi = 0; mi < 2; ++mi)
#pragma unroll
    for (int d = 0; d < 4; ++d) o[mi][d] = (f32x4){0.f, 0.f, 0.f, 0.f};
  float m[8], l[8];
#pragma unroll
  for (int i = 0; i < 8; ++i) { m[i] = NEG_INF; l[i] = 0.f; }

  // staging thread roles
  const int skey = tid >> 3, sco = (tid & 7) * 8;     // K: 2 rounds of 32 keys
  const int vkp  = tid >> 3, vc8 = (tid & 7) * 8;     // V: key-pair 2*vkp, cols vc8..+7

  const int nkt = qblk * 2 + 2;   // 64-key tiles covering [0, q0+128)
  for (int t = 0; t < nkt; ++t) {
    const int kt = t * 64;
    // issue global loads first (overlap with prior-iter compute drain)
    const size_t krow0 = ((size_t)(b * SEQ + kt + skey)) * D_MODEL + h * DKH + sco;
    const size_t krow1 = ((size_t)(b * SEQ + kt + 32 + skey)) * D_MODEL + h * DKH + sco;
    uint4 kv0 = *(const uint4*)(Kg + krow0);
    uint4 kv1 = *(const uint4*)(Kg + krow1);
    const size_t vrow0 = ((size_t)(b * SEQ + kt + 2 * vkp)) * D_MODEL + h * DKH + vc8;
    uint4 vv0 = *(const uint4*)(Vg + vrow0);
    uint4 vv1 = *(const uint4*)(Vg + vrow0 + D_MODEL);

    if (t) __syncthreads();        // prior-iter LDS reads complete
    *(uint4*)&Ks[skey][sco]      = kv0;
    *(uint4*)&Ks[32 + skey][sco] = kv1;
    {  // transpose V: pack key-pair into u32, store into [dk][key] rows (2-way banks)
      union { uint4 u; u16 s[8]; } a, c;
      a.u = vv0; c.u = vv1;
      u32* V32 = (u32*)&Vs[0][0];
#pragma unroll
      for (int j = 0; j < 8; ++j)
        V32[(vc8 + j) * 34 + vkp] = (u32)a.s[j] | ((u32)c.s[j] << 16);
    }
    __syncthreads();

    // S = Q K^T : sc[m-tile][n-tile]
    f32x4 sc[2][4];
#pragma unroll
    for (int nt = 0; nt < 4; ++nt) {
      bf16x8 b0 = *(const bf16x8*)&Ks[nt * 16 + l16][quad * 8];
      bf16x8 b1 = *(const bf16x8*)&Ks[nt * 16 + l16][32 + quad * 8];
#pragma unroll
      for (int mi = 0; mi < 2; ++mi) {
        f32x4 c = (f32x4){0.f, 0.f, 0.f, 0.f};
        c = __builtin_amdgcn_mfma_f32_16x16x32_bf16(qf[mi][0], b0, c, 0, 0, 0);
        c = __builtin_amdgcn_mfma_f32_16x16x32_bf16(qf[mi][1], b1, c, 0, 0, 0);
        sc[mi][nt] = c;
      }
    }

    // scale (log2 domain) + causal mask (only last 2 tiles can be masked)
    if (t >= nkt - 2) {
#pragma unroll
      for (int mi = 0; mi < 2; ++mi) {
        const int qrow = q0 + wave * 32 + mi * 16 + quad * 4;
#pragma unroll
        for (int nt = 0; nt < 4; ++nt)
#pragma unroll
          for (int r = 0; r < 4; ++r) {
            int key = kt + nt * 16 + l16;
            float v = sc[mi][nt][r] * SCALE_LOG2;
            sc[mi][nt][r] = (key <= qrow + r) ? v : NEG_INF;
          }
      }
    } else {
#pragma unroll
      for (int mi = 0; mi < 2; ++mi)
#pragma unroll
        for (int nt = 0; nt < 4; ++nt)
#pragma unroll
          for (int r = 0; r < 4; ++r)
            sc[mi][nt][r] *= SCALE_LOG2;
    }

    // online softmax (8 independent rows -> ILP over shfl chains)
#pragma unroll
    for (int mi = 0; mi < 2; ++mi)
#pragma unroll
      for (int r = 0; r < 4; ++r) {
        const int ri = mi * 4 + r;
        float mr = fmaxf(fmaxf(sc[mi][0][r], sc[mi][1][r]),
                         fmaxf(sc[mi][2][r], sc[mi][3][r]));
        mr = fmaxf(mr, __shfl_xor(mr, 1));
        mr = fmaxf(mr, __shfl_xor(mr, 2));
        mr = fmaxf(mr, __shfl_xor(mr, 4));
        mr = fmaxf(mr, __shfl_xor(mr, 8));
        float mnew  = fmaxf(m[ri], mr);
        float alpha = __builtin_amdgcn_exp2f(m[ri] - mnew);
        float p0 = __builtin_amdgcn_exp2f(sc[mi][0][r] - mnew);
        float p1 = __builtin_amdgcn_exp2f(sc[mi][1][r] - mnew);
        float p2 = __builtin_amdgcn_exp2f(sc[mi][2][r] - mnew);
        float p3 = __builtin_amdgcn_exp2f(sc[mi][3][r] - mnew);
        float rs = (p0 + p1) + (p2 + p3);
        rs += __shfl_xor(rs, 1);
        rs += __shfl_xor(rs, 2);
        rs += __shfl_xor(rs, 4);
        rs += __shfl_xor(rs, 8);
        l[ri] = alpha * l[ri] + rs;
        m[ri] = mnew;
#pragma unroll
        for (int d = 0; d < 4; ++d) o[mi][d][r] *= alpha;
        const int prow = mi * 16 + quad * 4 + r;
        Ps[wave][prow][l16]      = f2bf(p0);
        Ps[wave][prow][16 + l16] = f2bf(p1);
        Ps[wave][prow][32 + l16] = f2bf(p2);
        Ps[wave][prow][48 + l16] = f2bf(p3);
      }
    // Ps is per-wave: no barrier needed (compiler inserts lgkmcnt wait)

    // O += P V
#pragma unroll
    for (int kc = 0; kc < 2; ++kc) {
      bf16x8 pf[2];
#pragma unroll
      for (int mi = 0; mi < 2; ++mi)
        pf[mi] = *(const bf16x8*)&Ps[wave][mi * 16 + l16][kc * 32 + quad * 8];
#pragma unroll
      for (int d = 0; d < 4; ++d) {
        union { uint2 u2[2]; bf16x8 v; } vf;
        const u16* vp = &Vs[d * 16 + l16][kc * 32 + quad * 8];
        vf.u2[0] = *(const uint2*)(vp);
        vf.u2[1] = *(const uint2*)(vp + 4);
#pragma unroll
        for (int mi = 0; mi < 2; ++mi)
          o[mi][d] = __builtin_amdgcn_mfma_f32_16x16x32_bf16(pf[mi], vf.v, o[mi][d], 0, 0, 0);
      }
    }
    __syncthreads();   // all waves done with Ks/Vs before next stage
  }

  // normalize and store
#pragma unroll
  for (int mi = 0; mi < 2; ++mi)
#pragma unroll
    for (int d = 0; d < 4; ++d)
#pragma unroll
      for (int r = 0; r < 4; ++r) {
        int s = q0 + wave * 32 + mi * 16 + quad * 4 + r;
        O[((size_t)(b * SEQ + s)) * D_MODEL + h * DKH + d * 16 + l16] =
            f2bf(o[mi][d][r] / l[mi * 4 + r]);
      }
}

// ---------------- launch ----------------
extern "C" void kernel_launch(void* const* d_in, const int* in_sizes, int n_in,
                              void* d_out, int out_size, void* d_ws, size_t ws_size,
                              hipStream_t stream) {
  const float* x      = (const float*)d_in[0];
  const int*   tokpos = (const int*)d_in[1];
  const float* wq     = (const float*)d_in[2];
  const float* wk     = (const float*)d_in[3];
  const float* wv     = (const float*)d_in[4];
  const float* wo     = (const float*)d_in[5];
  float* out = (float*)d_out;

  char* ws = (char*)d_ws;
  u16* Xb  = (u16*)(ws + 0);           // 16 MB (also Ob)
  u16* Wqb = (u16*)(ws + 16777216);
  u16* Wkb = (u16*)(ws + 18874368);
  u16* Wvb = (u16*)(ws + 20971520);
  u16* Wob = (u16*)(ws + 23068672);
  u16* Qb  = (u16*)(ws + 25165824);
  u16* Kb  = (u16*)(ws + 41943040);
  u16* Vb  = (u16*)(ws + 58720256);
  u16* Ob  = Xb;

  const int nX = BATCH * SEQ * D_MODEL;
  const int nW = D_MODEL * D_MODEL;

  cvt_f32_bf16<<<nX / 1024, 256, 0, stream>>>(x,  Xb,  nX);
  cvt_f32_bf16<<<nW / 1024, 256, 0, stream>>>(wq, Wqb, nW);
  cvt_f32_bf16<<<nW / 1024, 256, 0, stream>>>(wk, Wkb, nW);
  cvt_f32_bf16<<<nW / 1024, 256, 0, stream>>>(wv, Wvb, nW);
  cvt_f32_bf16<<<nW / 1024, 256, 0, stream>>>(wo, Wob, nW);

  dim3 gg(D_MODEL / 128, M_ROWS / 128);
  gemm_bt<1><<<gg, 256, 0, stream>>>(Xb, Wqb, Qb, M_ROWS, D_MODEL, D_MODEL);
  gemm_bt<1><<<gg, 256, 0, stream>>>(Xb, Wkb, Kb, M_ROWS, D_MODEL, D_MODEL);
  gemm_bt<1><<<gg, 256, 0, stream>>>(Xb, Wvb, Vb, M_ROWS, D_MODEL, D_MODEL);

  rope_kernel<<<(BATCH * SEQ * (D_MODEL / 2)) / 256, 256, 0, stream>>>(
      Qb, Kb, tokpos, BATCH * SEQ * (D_MODEL / 2));

  flash_attn<<<dim3(SEQ / 128, BATCH * NH), 256, 0, stream>>>(Qb, Kb, Vb, Ob);

  gemm_bt<0><<<gg, 256, 0, stream>>>(Ob, Wob, out, M_ROWS, D_MODEL, D_MODEL);
}

// Round 3
// 300.601 us; speedup vs baseline: 2.2657x; 1.4902x over previous
//
#include <hip/hip_runtime.h>

// multihead self-attention: B=4 S=2048 D=1024 H=16 DK=64, causal, RoPE(theta=1e4)
// cvt->bf16 | QKV = x*Wqkv^T (one mfma gemm, global_load_lds staging) | rope |
// flash attention (static-max softmax, no shuffles, l via mfma(P,ones)) | out gemm

#define D_MODEL 1024
#define NH      16
#define DKH     64
#define SEQ     2048
#define BATCH   4
#define M_ROWS  (BATCH * SEQ)   // 8192
#define SCALE_LOG2 0.180336875461f   // (1/sqrt(64)) * log2(e)
#define M2OFF      16.0f             // static softmax max (log2 domain)
#define NEG_INF    (-__builtin_inff())

typedef __bf16 bf16x8 __attribute__((ext_vector_type(8)));
typedef float  f32x4  __attribute__((ext_vector_type(4)));
typedef unsigned short u16;
typedef unsigned int   u32;

__device__ __forceinline__ u16 f2bf(float f) {
  u32 u = __float_as_uint(f);
  u = (u + 0x7fffu + ((u >> 16) & 1u)) >> 16;   // RNE
  return (u16)u;
}
__device__ __forceinline__ float bf2f(u16 h) {
  return __uint_as_float(((u32)h) << 16);
}
__device__ __forceinline__ void glds16(const void* g, void* l) {
  __builtin_amdgcn_global_load_lds((const __attribute__((address_space(1))) void*)g,
                                   (__attribute__((address_space(3))) void*)l, 16, 0, 0);
}

// ---------------- f32 -> bf16 convert ----------------
__global__ void cvt_f32_bf16(const float* __restrict__ in, u16* __restrict__ out, int n) {
  int i = (blockIdx.x * blockDim.x + threadIdx.x) * 4;
  if (i >= n) return;
  float4 v = *(const float4*)(in + i);
  uint2 o;
  o.x = (u32)f2bf(v.x) | ((u32)f2bf(v.y) << 16);
  o.y = (u32)f2bf(v.z) | ((u32)f2bf(v.w) << 16);
  *(uint2*)(out + i) = o;
}

// ---- GEMM C[M,N] = A[M,K]*W[N,K]^T, 128x128 tile, BK=64, global_load_lds staging.
// LDS unpadded [128][64], chunk c of row stored at position c^(row&7) (xor swizzle):
// staging is lane-contiguous (glds requirement), frag reads spread across 16B slots.
// MODE 0: f32 single output (stride 1024). MODE 1: bf16 out split Q/K/V by n0.
template<int MODE>
__global__ __launch_bounds__(256) void gemm_glds(const u16* __restrict__ A,
                                                 const u16* __restrict__ W,
                                                 void* __restrict__ C0,
                                                 void* __restrict__ C1,
                                                 void* __restrict__ C2,
                                                 int K) {
  __shared__ u16 As[128][64];
  __shared__ u16 Bs[128][64];
  const int tid  = threadIdx.x;
  const int m0   = blockIdx.y * 128;
  const int n0   = blockIdx.x * 128;
  const int wave = tid >> 6, lane = tid & 63;
  const int quad = lane >> 4, l16 = lane & 15;
  const int wm = (wave >> 1) * 64, wn = (wave & 1) * 64;

  f32x4 acc[4][4];
#pragma unroll
  for (int i = 0; i < 4; ++i)
#pragma unroll
    for (int j = 0; j < 4; ++j) acc[i][j] = (f32x4){0.f, 0.f, 0.f, 0.f};

  for (int k0 = 0; k0 < K; k0 += 64) {
    if (k0) __syncthreads();                 // prior-iter LDS reads done
#pragma unroll
    for (int i = 0; i < 4; ++i) {            // 4 rounds x 256 lanes x 16B per tile
      int ci  = i * 256 + tid;
      int row = ci >> 3;
      int gc  = (ci & 7) ^ (row & 7);        // xor-swizzled global chunk
      u16* lbase = &As[0][0] + (size_t)(i * 256 + (tid & 192)) * 8;  // wave-uniform
      glds16(A + (size_t)(m0 + row) * K + k0 + gc * 8, lbase);
      lbase = &Bs[0][0] + (size_t)(i * 256 + (tid & 192)) * 8;
      glds16(W + (size_t)(n0 + row) * K + k0 + gc * 8, lbase);
    }
    __syncthreads();                         // drains vmcnt (glds) for all waves
#pragma unroll
    for (int kk = 0; kk < 64; kk += 32) {
      const int cb = kk >> 3;
      bf16x8 af[4], bfr[4];
#pragma unroll
      for (int mi = 0; mi < 4; ++mi) {
        int r = wm + mi * 16 + l16;
        af[mi] = *(const bf16x8*)(&As[0][0] + r * 64 + (((cb + quad) ^ (r & 7)) << 3));
      }
#pragma unroll
      for (int ni = 0; ni < 4; ++ni) {
        int r = wn + ni * 16 + l16;
        bfr[ni] = *(const bf16x8*)(&Bs[0][0] + r * 64 + (((cb + quad) ^ (r & 7)) << 3));
      }
#pragma unroll
      for (int mi = 0; mi < 4; ++mi)
#pragma unroll
        for (int ni = 0; ni < 4; ++ni)
          acc[mi][ni] = __builtin_amdgcn_mfma_f32_16x16x32_bf16(af[mi], bfr[ni], acc[mi][ni], 0, 0, 0);
    }
  }

  // epilogue: C layout col=lane&15, row=quad*4+reg
  if (MODE == 1) {
    u16* dst; int nb;
    if (n0 < 1024)      { dst = (u16*)C0; nb = n0; }
    else if (n0 < 2048) { dst = (u16*)C1; nb = n0 - 1024; }
    else                { dst = (u16*)C2; nb = n0 - 2048; }
#pragma unroll
    for (int mi = 0; mi < 4; ++mi)
#pragma unroll
      for (int ni = 0; ni < 4; ++ni)
#pragma unroll
        for (int r = 0; r < 4; ++r) {
          int row = m0 + wm + mi * 16 + quad * 4 + r;
          int col = nb + wn + ni * 16 + l16;
          dst[(size_t)row * 1024 + col] = f2bf(acc[mi][ni][r]);
        }
  } else {
    float* dst = (float*)C0;
#pragma unroll
    for (int mi = 0; mi < 4; ++mi)
#pragma unroll
      for (int ni = 0; ni < 4; ++ni)
#pragma unroll
        for (int r = 0; r < 4; ++r) {
          int row = m0 + wm + mi * 16 + quad * 4 + r;
          int col = n0 + wn + ni * 16 + l16;
          dst[(size_t)row * 1024 + col] = acc[mi][ni][r];
        }
  }
}

// ---------------- RoPE in-place on bf16 Q and K ----------------
__global__ void rope_kernel(u16* __restrict__ Q, u16* __restrict__ Kb,
                            const int* __restrict__ pos, int npairs) {
  int p = blockIdx.x * blockDim.x + threadIdx.x;
  if (p >= npairs) return;
  int i = p & 31;
  int s = (p >> 9) & (SEQ - 1);
  float inv = expf((float)i * -0.28782313662425574f);  // ln(1e4)/32
  float ang = (float)pos[s] * inv;
  float c = cosf(ang), sn = sinf(ang);

  u32 qp = *(u32*)(Q + 2 * (size_t)p);
  float qe = bf2f((u16)(qp & 0xffff)), qo = bf2f((u16)(qp >> 16));
  *(u32*)(Q + 2 * (size_t)p) =
      (u32)f2bf(qe * c - qo * sn) | ((u32)f2bf(qe * sn + qo * c) << 16);

  u32 kp = *(u32*)(Kb + 2 * (size_t)p);
  float ke = bf2f((u16)(kp & 0xffff)), ko = bf2f((u16)(kp >> 16));
  *(u32*)(Kb + 2 * (size_t)p) =
      (u32)f2bf(ke * c - ko * sn) | ((u32)f2bf(ke * sn + ko * c) << 16);
}

// ---------------- causal flash attention ----------------
// grid (16, B*H); block 256 = 4 waves, wave owns 32 q-rows. 64-key tiles.
// Static-max softmax: p = exp2(s*scale*log2e - 16); no shuffles, no running m/l.
// Row-sum l computed by mfma(P, ones) -> exactly matches stored bf16 P.
__global__ __launch_bounds__(256, 4) void flash_attn(const u16* __restrict__ Q,
                                                     const u16* __restrict__ Kg,
                                                     const u16* __restrict__ Vg,
                                                     u16* __restrict__ O) {
  __shared__ u16 Ks[64][72];       // [key][dk], padded (2-way banks)
  __shared__ u32 Vs[64][35];       // [dk][key-pair], odd stride -> ~2-way banks
  __shared__ u16 Ps[4][32][72];    // per-wave P 32x64, A-operand layout

  const int tid  = threadIdx.x;
  const int xr   = blockIdx.x;
  const int qblk = (xr & 1) ? (xr >> 1) : (15 - (xr >> 1));   // long+short interleave
  const int q0   = qblk * 128;
  const int bh   = blockIdx.y;
  const int b    = bh >> 4, h = bh & 15;
  const int wave = tid >> 6, lane = tid & 63;
  const int quad = lane >> 4, l16 = lane & 15;

  bf16x8 qf[2][2];
#pragma unroll
  for (int mi = 0; mi < 2; ++mi) {
    int s = q0 + wave * 32 + mi * 16 + l16;
    const u16* qp = Q + ((size_t)(b * SEQ + s)) * D_MODEL + h * DKH + quad * 8;
    qf[mi][0] = *(const bf16x8*)(qp);
    qf[mi][1] = *(const bf16x8*)(qp + 32);
  }

  f32x4 o[2][4], ol[2];
#pragma unroll
  for (int mi = 0; mi < 2; ++mi) {
    ol[mi] = (f32x4){0.f, 0.f, 0.f, 0.f};
#pragma unroll
    for (int d = 0; d < 4; ++d) o[mi][d] = (f32x4){0.f, 0.f, 0.f, 0.f};
  }
  union { u32 x[4]; bf16x8 v; } ones;
  ones.x[0] = ones.x[1] = ones.x[2] = ones.x[3] = 0x3f803f80u;  // bf16 1.0 x8

  const int skey = tid >> 3, sco = (tid & 7) * 8;
  const int vkp  = tid >> 3, vc8 = (tid & 7) * 8;

  const int nkt = qblk * 2 + 2;
  for (int t = 0; t < nkt; ++t) {
    const int kt = t * 64;
    // global loads issue early (overlap prior-iter MFMA drain)
    const size_t krow0 = ((size_t)(b * SEQ + kt + skey)) * D_MODEL + h * DKH + sco;
    uint4 kv0 = *(const uint4*)(Kg + krow0);
    uint4 kv1 = *(const uint4*)(Kg + krow0 + (size_t)32 * D_MODEL);
    const size_t vrow0 = ((size_t)(b * SEQ + kt + 2 * vkp)) * D_MODEL + h * DKH + vc8;
    uint4 vv0 = *(const uint4*)(Vg + vrow0);
    uint4 vv1 = *(const uint4*)(Vg + vrow0 + D_MODEL);

    if (t) __syncthreads();        // all waves done reading Ks/Vs from prior tile
    *(uint4*)&Ks[skey][sco]      = kv0;
    *(uint4*)&Ks[32 + skey][sco] = kv1;
    {  // V transpose: key-pair packed u32, [dk][kp]
      union { uint4 u; u16 s[8]; } a, c;
      a.u = vv0; c.u = vv1;
#pragma unroll
      for (int j = 0; j < 8; ++j)
        Vs[vc8 + j][vkp] = (u32)a.s[j] | ((u32)c.s[j] << 16);
    }
    __syncthreads();

    // S = Q K^T
    f32x4 sc[2][4];
#pragma unroll
    for (int nt = 0; nt < 4; ++nt) {
      bf16x8 b0 = *(const bf16x8*)&Ks[nt * 16 + l16][quad * 8];
      bf16x8 b1 = *(const bf16x8*)&Ks[nt * 16 + l16][32 + quad * 8];
#pragma unroll
      for (int mi = 0; mi < 2; ++mi) {
        f32x4 c = (f32x4){0.f, 0.f, 0.f, 0.f};
        c = __builtin_amdgcn_mfma_f32_16x16x32_bf16(qf[mi][0], b0, c, 0, 0, 0);
        c = __builtin_amdgcn_mfma_f32_16x16x32_bf16(qf[mi][1], b1, c, 0, 0, 0);
        sc[mi][nt] = c;
      }
    }

    // causal mask (last two tiles only); exp2(-inf)=0 handles masked lanes
    if (t >= nkt - 2) {
#pragma unroll
      for (int mi = 0; mi < 2; ++mi) {
        const int qrow = q0 + wave * 32 + mi * 16 + quad * 4;
#pragma unroll
        for (int nt = 0; nt < 4; ++nt)
#pragma unroll
          for (int r = 0; r < 4; ++r) {
            int key = kt + nt * 16 + l16;
            sc[mi][nt][r] = (key <= qrow + r) ? sc[mi][nt][r] : NEG_INF;
          }
      }
    }

    // p = exp2(s*scale - 16), store bf16 (RN) to per-wave Ps (no barrier needed)
#pragma unroll
    for (int mi = 0; mi < 2; ++mi) {
      const int pr = mi * 16 + quad * 4;
#pragma unroll
      for (int nt = 0; nt < 4; ++nt)
#pragma unroll
        for (int r = 0; r < 4; ++r) {
          float p = __builtin_amdgcn_exp2f(fmaf(sc[mi][nt][r], SCALE_LOG2, -M2OFF));
          Ps[wave][pr + r][nt * 16 + l16] = (u16)((__float_as_uint(p) + 0x8000u) >> 16);
        }
    }

    // O += P V ; l += P*ones (row sums)
#pragma unroll
    for (int kc = 0; kc < 2; ++kc) {
      bf16x8 pf[2];
#pragma unroll
      for (int mi = 0; mi < 2; ++mi) {
        pf[mi] = *(const bf16x8*)&Ps[wave][mi * 16 + l16][kc * 32 + quad * 8];
        ol[mi] = __builtin_amdgcn_mfma_f32_16x16x32_bf16(pf[mi], ones.v, ol[mi], 0, 0, 0);
      }
#pragma unroll
      for (int d = 0; d < 4; ++d) {
        union { u32 x[4]; bf16x8 v; } vf;
        const u32* vp = &Vs[d * 16 + l16][kc * 16 + quad * 4];
        vf.x[0] = vp[0]; vf.x[1] = vp[1]; vf.x[2] = vp[2]; vf.x[3] = vp[3];
#pragma unroll
        for (int mi = 0; mi < 2; ++mi)
          o[mi][d] = __builtin_amdgcn_mfma_f32_16x16x32_bf16(pf[mi], vf.v, o[mi][d], 0, 0, 0);
      }
    }
  }

  // normalize and store
#pragma unroll
  for (int mi = 0; mi < 2; ++mi)
#pragma unroll
    for (int r = 0; r < 4; ++r) {
      float inv = __builtin_amdgcn_rcpf(ol[mi][r]);
      int s = q0 + wave * 32 + mi * 16 + quad * 4 + r;
#pragma unroll
      for (int d = 0; d < 4; ++d)
        O[((size_t)(b * SEQ + s)) * D_MODEL + h * DKH + d * 16 + l16] =
            f2bf(o[mi][d][r] * inv);
    }
}

// ---------------- launch ----------------
extern "C" void kernel_launch(void* const* d_in, const int* in_sizes, int n_in,
                              void* d_out, int out_size, void* d_ws, size_t ws_size,
                              hipStream_t stream) {
  const float* x      = (const float*)d_in[0];
  const int*   tokpos = (const int*)d_in[1];
  const float* wq     = (const float*)d_in[2];
  const float* wk     = (const float*)d_in[3];
  const float* wv     = (const float*)d_in[4];
  const float* wo     = (const float*)d_in[5];
  float* out = (float*)d_out;

  char* ws = (char*)d_ws;
  u16* Xb  = (u16*)(ws + 0);           // 16 MB (also Ob)
  u16* Wqb = (u16*)(ws + 16777216);    // Wq,Wk,Wv contiguous -> one [3072][1024]
  u16* Wkb = (u16*)(ws + 18874368);
  u16* Wvb = (u16*)(ws + 20971520);
  u16* Wob = (u16*)(ws + 23068672);
  u16* Qb  = (u16*)(ws + 25165824);
  u16* Kb  = (u16*)(ws + 41943040);
  u16* Vb  = (u16*)(ws + 58720256);
  u16* Ob  = Xb;

  const int nX = BATCH * SEQ * D_MODEL;
  const int nW = D_MODEL * D_MODEL;

  cvt_f32_bf16<<<nX / 1024, 256, 0, stream>>>(x,  Xb,  nX);
  cvt_f32_bf16<<<nW / 1024, 256, 0, stream>>>(wq, Wqb, nW);
  cvt_f32_bf16<<<nW / 1024, 256, 0, stream>>>(wk, Wkb, nW);
  cvt_f32_bf16<<<nW / 1024, 256, 0, stream>>>(wv, Wvb, nW);
  cvt_f32_bf16<<<nW / 1024, 256, 0, stream>>>(wo, Wob, nW);

  // fused QKV projection: C[8192,3072] = X * Wqkv^T, split to Qb/Kb/Vb
  gemm_glds<1><<<dim3(24, 64), 256, 0, stream>>>(Xb, Wqb, Qb, Kb, Vb, D_MODEL);

  rope_kernel<<<(BATCH * SEQ * (D_MODEL / 2)) / 256, 256, 0, stream>>>(
      Qb, Kb, tokpos, BATCH * SEQ * (D_MODEL / 2));

  flash_attn<<<dim3(16, BATCH * NH), 256, 0, stream>>>(Qb, Kb, Vb, Ob);

  gemm_glds<0><<<dim3(8, 64), 256, 0, stream>>>(Ob, Wob, out, nullptr, nullptr, D_MODEL);
}

// Round 5
// 284.619 us; speedup vs baseline: 2.3929x; 1.0562x over previous
//
#include <hip/hip_runtime.h>

// multihead self-attention: B=4 S=2048 D=1024 H=16 DK=64, causal, RoPE(theta=1e4)
// f16 pipeline: cvt | QKV = x*Wqkv^T (m97-pattern mfma gemm) | rope |
// transposed flash (S^T=K*Q^T, O^T=V^T*P^T, P register-resident) | out gemm (f32)

#define D_MODEL 1024
#define NH      16
#define DKH     64
#define SEQ     2048
#define BATCH   4
#define M_ROWS  (BATCH * SEQ)   // 8192
#define SCALE_LOG2 0.180336875461f   // (1/sqrt(64)) * log2(e)
#define M2OFF      8.0f              // static softmax offset (keeps P in f16 normal range)

typedef _Float16 f16;
typedef _Float16 f16x8 __attribute__((ext_vector_type(8)));
typedef _Float16 f16x4 __attribute__((ext_vector_type(4)));
typedef _Float16 f16x2 __attribute__((ext_vector_type(2)));
typedef __fp16   fp16x2n __attribute__((ext_vector_type(2)));   // cvt_pkrtz native type
typedef float    f32x4 __attribute__((ext_vector_type(4)));
typedef unsigned short u16;
typedef unsigned int   u32;

__device__ __forceinline__ void glds16(const void* g, void* l) {
  __builtin_amdgcn_global_load_lds((const __attribute__((address_space(1))) void*)g,
                                   (__attribute__((address_space(3))) void*)l, 16, 0, 0);
}
__device__ __forceinline__ u32 pk(float a, float b) {
  union { fp16x2n h; u32 u; } c; c.h = __builtin_amdgcn_cvt_pkrtz(a, b); return c.u;
}

// ---------------- f32 -> f16 convert ----------------
__global__ void cvt_f32_f16(const float* __restrict__ in, f16* __restrict__ out, int n) {
  int i = (blockIdx.x * blockDim.x + threadIdx.x) * 4;
  if (i >= n) return;
  float4 v = *(const float4*)(in + i);
  uint2 o; o.x = pk(v.x, v.y); o.y = pk(v.z, v.w);
  *(uint2*)(out + i) = o;
}

// ---- GEMM C[M,N] = A[M,K]*W[N,K]^T, 128x128 tile, BK=64, m97 pattern:
// unpadded LDS [128][64], linear glds16 staging, plain b128 frag reads.
// MODE 0: f32 out. MODE 1: f16 out split Q/K/V by n0.
template<int MODE>
__global__ __launch_bounds__(256) void gemm_glds(const f16* __restrict__ A,
                                                 const f16* __restrict__ W,
                                                 void* __restrict__ C0,
                                                 void* __restrict__ C1,
                                                 void* __restrict__ C2,
                                                 int K) {
  __shared__ f16 As[128][64];
  __shared__ f16 Bs[128][64];
  const int tid  = threadIdx.x;
  const int m0   = blockIdx.y * 128;
  const int n0   = blockIdx.x * 128;
  const int wave = tid >> 6, lane = tid & 63;
  const int quad = lane >> 4, l16 = lane & 15;
  const int wm = (wave >> 1) * 64, wn = (wave & 1) * 64;

  f32x4 acc[4][4];
#pragma unroll
  for (int i = 0; i < 4; ++i)
#pragma unroll
    for (int j = 0; j < 4; ++j) acc[i][j] = (f32x4){0.f, 0.f, 0.f, 0.f};

  for (int k0 = 0; k0 < K; k0 += 64) {
    if (k0) __syncthreads();
#pragma unroll
    for (int i = 0; i < 4; ++i) {            // 4 rounds x 256 lanes x 16B per buffer
      int ci  = i * 256 + tid;
      int row = ci >> 3, ch = ci & 7;
      glds16(A + (size_t)(m0 + row) * K + k0 + ch * 8,
             (char*)&As[0][0] + (size_t)(i * 256 + (tid & 192)) * 16);
      glds16(W + (size_t)(n0 + row) * K + k0 + ch * 8,
             (char*)&Bs[0][0] + (size_t)(i * 256 + (tid & 192)) * 16);
    }
    __syncthreads();                         // drains glds vmcnt for all waves
#pragma unroll
    for (int kk = 0; kk < 64; kk += 32) {
      f16x8 af[4], bfr[4];
#pragma unroll
      for (int mi = 0; mi < 4; ++mi)
        af[mi] = *(const f16x8*)&As[wm + mi * 16 + l16][kk + quad * 8];
#pragma unroll
      for (int ni = 0; ni < 4; ++ni)
        bfr[ni] = *(const f16x8*)&Bs[wn + ni * 16 + l16][kk + quad * 8];
#pragma unroll
      for (int mi = 0; mi < 4; ++mi)
#pragma unroll
        for (int ni = 0; ni < 4; ++ni)
          acc[mi][ni] = __builtin_amdgcn_mfma_f32_16x16x32_f16(af[mi], bfr[ni], acc[mi][ni], 0, 0, 0);
    }
  }

  // epilogue: C layout col=lane&15, row=quad*4+reg
  if (MODE == 1) {
    f16* dst; int nb;
    if (n0 < 1024)      { dst = (f16*)C0; nb = n0; }
    else if (n0 < 2048) { dst = (f16*)C1; nb = n0 - 1024; }
    else                { dst = (f16*)C2; nb = n0 - 2048; }
#pragma unroll
    for (int mi = 0; mi < 4; ++mi)
#pragma unroll
      for (int ni = 0; ni < 4; ++ni)
#pragma unroll
        for (int r = 0; r < 4; ++r) {
          int row = m0 + wm + mi * 16 + quad * 4 + r;
          int col = nb + wn + ni * 16 + l16;
          dst[(size_t)row * 1024 + col] = (f16)acc[mi][ni][r];
        }
  } else {
    float* dst = (float*)C0;
#pragma unroll
    for (int mi = 0; mi < 4; ++mi)
#pragma unroll
      for (int ni = 0; ni < 4; ++ni)
#pragma unroll
        for (int r = 0; r < 4; ++r) {
          int row = m0 + wm + mi * 16 + quad * 4 + r;
          int col = n0 + wn + ni * 16 + l16;
          dst[(size_t)row * 1024 + col] = acc[mi][ni][r];
        }
  }
}

// ---------------- RoPE in-place on f16 Q and K ----------------
__global__ void rope_kernel(f16* __restrict__ Q, f16* __restrict__ Kb,
                            const int* __restrict__ pos, int npairs) {
  int p = blockIdx.x * blockDim.x + threadIdx.x;
  if (p >= npairs) return;
  int i = p & 31;
  int s = (p >> 9) & (SEQ - 1);
  float inv = __builtin_amdgcn_exp2f(-0.41524101186092029f * (float)i); // log2(1e4)/32
  float ang = (float)pos[s] * inv;
  float c = cosf(ang), sn = sinf(ang);

  union { u32 u; f16x2 h; } uq, uk;
  uq.u = *(u32*)(Q + 2 * (size_t)p);
  float qe = (float)uq.h[0], qo = (float)uq.h[1];
  *(u32*)(Q + 2 * (size_t)p) = pk(qe * c - qo * sn, qe * sn + qo * c);

  uk.u = *(u32*)(Kb + 2 * (size_t)p);
  float ke = (float)uk.h[0], ko = (float)uk.h[1];
  *(u32*)(Kb + 2 * (size_t)p) = pk(ke * c - ko * sn, ke * sn + ko * c);
}

// ---------------- transposed causal flash attention ----------------
// grid (B*H, 32); block 256 = 4 waves. Block owns 64 q-rows; KV-tiles of 128 keys,
// wave w owns keys [kt+32w, kt+32w+32). S^T = K*Q^T (16x16x32_f16, C: key=quad*4+r,
// q=l16) -> static-max exp2 -> P^T stays in registers as B-operand of 16x16x16_f16:
// O^T += V^T * P^T. Cross-wave O/l reduction once per block via LDS.
__global__ __launch_bounds__(256, 3) void flash_attn(const f16* __restrict__ Q,
                                                     const f16* __restrict__ Kg,
                                                     const f16* __restrict__ Vg,
                                                     f16* __restrict__ O) {
  __shared__ char smem[33280];
  f16   (*Ks)[64]  = (f16(*)[64])smem;            // [128][64] key x dk, 16 KB
  u32   (*Vt)[65]  = (u32(*)[65])(smem + 16384);  // [64][65] dk x key-pair, 16.6 KB
  float (*Red)[66] = (float(*)[66])smem;          // reduction [64 dk][66], aliases Ks
  float (*Lbuf)[4] = (float(*)[4])(smem + 17408); // [64 q][quad], inside dead Vt

  const int tid  = threadIdx.x;
  const int bh   = blockIdx.x;
  const int b    = bh >> 4, h = bh & 15;
  const int qblk = 31 - (int)blockIdx.y;          // longest first
  const int q0   = qblk * 64;
  const int wave = tid >> 6, lane = tid & 63;
  const int quad = lane >> 4, l16 = lane & 15;
  const int nkt  = (qblk + 2) >> 1;               // 128-key tiles covering q0+64 keys

  // Q B-frags: B[k=dk][n=q] = Q[q=l16][dk=quad*8+j], per (nt, kstep)
  f16x8 qf[4][2];
#pragma unroll
  for (int nt = 0; nt < 4; ++nt)
#pragma unroll
    for (int ks = 0; ks < 2; ++ks)
      qf[nt][ks] = *(const f16x8*)(Q + ((size_t)(b * SEQ + q0 + nt * 16 + l16)) * D_MODEL
                                     + h * DKH + ks * 32 + quad * 8);

  f32x4 o[4][4];        // O^T partial: [dk-mtile][q-ntile], C layout dk=quad*4+r, q=l16
#pragma unroll
  for (int md = 0; md < 4; ++md)
#pragma unroll
    for (int nt = 0; nt < 4; ++nt) o[md][nt] = (f32x4){0.f, 0.f, 0.f, 0.f};
  float lacc[4] = {0.f, 0.f, 0.f, 0.f};

  const int kp = tid >> 3, dc = (tid & 7) * 8;    // V-transpose staging role

  for (int t = 0; t < nkt; ++t) {
    const int kt = t * 128;
    // V global loads early (keys 2kp,2kp+1 and 64+2kp,65+2kp; dk dc..dc+7)
    const f16* vb = Vg + ((size_t)(b * SEQ + kt + 2 * kp)) * D_MODEL + h * DKH + dc;
    uint4 v0 = *(const uint4*)vb;
    uint4 v1 = *(const uint4*)(vb + D_MODEL);
    uint4 v2 = *(const uint4*)(vb + 64 * D_MODEL);
    uint4 v3 = *(const uint4*)(vb + 65 * D_MODEL);

    if (t) __syncthreads();          // all waves done with prior Ks/Vt
    // K staging via global_load_lds (lane-linear, m97 pattern)
#pragma unroll
    for (int i = 0; i < 4; ++i) {
      int ci = i * 256 + tid;
      int row = ci >> 3, ch = ci & 7;
      glds16(Kg + ((size_t)(b * SEQ + kt + row)) * D_MODEL + h * DKH + ch * 8,
             smem + (size_t)(i * 256 + (tid & 192)) * 16);
    }
    {  // V transpose: key-pairs packed u32, [dk][kp], odd stride 65 (2-way banks)
      union { uint4 u; u16 s[8]; } a0, a1, a2, a3;
      a0.u = v0; a1.u = v1; a2.u = v2; a3.u = v3;
#pragma unroll
      for (int j = 0; j < 8; ++j) {
        Vt[dc + j][kp]      = (u32)a0.s[j] | ((u32)a1.s[j] << 16);
        Vt[dc + j][32 + kp] = (u32)a2.s[j] | ((u32)a3.s[j] << 16);
      }
    }
    __syncthreads();                 // also drains glds vmcnt

    // S^T = K_slice * Q^T, then exp2 -> P^T B-frags (registers only)
    f16x4 pb[2][4];
#pragma unroll
    for (int mt = 0; mt < 2; ++mt) {
      const int krow = wave * 32 + mt * 16 + l16;
      f16x8 ka0 = *(const f16x8*)&Ks[krow][quad * 8];
      f16x8 ka1 = *(const f16x8*)&Ks[krow][32 + quad * 8];
      const int keyb = kt + wave * 32 + mt * 16 + quad * 4;
#pragma unroll
      for (int nt = 0; nt < 4; ++nt) {
        f32x4 c = (f32x4){0.f, 0.f, 0.f, 0.f};
        c = __builtin_amdgcn_mfma_f32_16x16x32_f16(ka0, qf[nt][0], c, 0, 0, 0);
        c = __builtin_amdgcn_mfma_f32_16x16x32_f16(ka1, qf[nt][1], c, 0, 0, 0);
        const int q = q0 + nt * 16 + l16;
#pragma unroll
        for (int r = 0; r < 4; ++r) {
          float p = __builtin_amdgcn_exp2f(fmaf(c[r], SCALE_LOG2, -M2OFF));
          if (t == nkt - 1) p = (keyb + r <= q) ? p : 0.f;   // causal (last tile only)
          lacc[nt] += p;
          pb[mt][nt][r] = (f16)p;
        }
      }
    }

    // O^T += V^T_slice * P^T  (16x16x16_f16, k = 16 keys per step)
#pragma unroll
    for (int md = 0; md < 4; ++md)
#pragma unroll
      for (int ks2 = 0; ks2 < 2; ++ks2) {
        const u32* vp = &Vt[md * 16 + l16][wave * 16 + ks2 * 8 + quad * 2];
        union { u32 x[2]; f16x4 v; } va;
        va.x[0] = vp[0]; va.x[1] = vp[1];
#pragma unroll
        for (int nt = 0; nt < 4; ++nt)
          o[md][nt] = __builtin_amdgcn_mfma_f32_16x16x16f16(va.v, pb[ks2][nt], o[md][nt], 0, 0, 0);
      }
  }

  __syncthreads();
  // cross-wave reduction of O^T and l (serial, once per block)
  for (int w = 0; w < 4; ++w) {
    if (wave == w) {
#pragma unroll
      for (int md = 0; md < 4; ++md)
#pragma unroll
        for (int nt = 0; nt < 4; ++nt)
#pragma unroll
          for (int r = 0; r < 4; ++r) {
            float* s = &Red[md * 16 + quad * 4 + r][nt * 16 + l16];
            if (w == 0) *s = o[md][nt][r]; else *s += o[md][nt][r];
          }
#pragma unroll
      for (int nt = 0; nt < 4; ++nt) {
        float* ls = &Lbuf[nt * 16 + l16][quad];
        if (w == 0) *ls = lacc[nt]; else *ls += lacc[nt];
      }
    }
    __syncthreads();
  }

  // normalize + store: thread -> (q, 16-dk chunk), 32B contiguous
  {
    const int q = tid & 63, dc4 = (tid >> 6) * 16;
    float lsum = Lbuf[q][0] + Lbuf[q][1] + Lbuf[q][2] + Lbuf[q][3];
    float linv = __builtin_amdgcn_rcpf(lsum);
    union { uint4 u[2]; u32 w[8]; } ov;
#pragma unroll
    for (int i = 0; i < 8; ++i)
      ov.w[i] = pk(Red[dc4 + 2 * i][q] * linv, Red[dc4 + 2 * i + 1][q] * linv);
    f16* op = O + ((size_t)(b * SEQ + q0 + q)) * D_MODEL + h * DKH + dc4;
    *(uint4*)op = ov.u[0];
    *(uint4*)(op + 8) = ov.u[1];
  }
}

// ---------------- launch ----------------
extern "C" void kernel_launch(void* const* d_in, const int* in_sizes, int n_in,
                              void* d_out, int out_size, void* d_ws, size_t ws_size,
                              hipStream_t stream) {
  const float* x      = (const float*)d_in[0];
  const int*   tokpos = (const int*)d_in[1];
  const float* wq     = (const float*)d_in[2];
  const float* wk     = (const float*)d_in[3];
  const float* wv     = (const float*)d_in[4];
  const float* wo     = (const float*)d_in[5];
  float* out = (float*)d_out;

  char* ws = (char*)d_ws;
  f16* Xb  = (f16*)(ws + 0);           // 16 MB (also Ob)
  f16* Wqb = (f16*)(ws + 16777216);    // Wq,Wk,Wv contiguous -> one [3072][1024]
  f16* Wkb = (f16*)(ws + 18874368);
  f16* Wvb = (f16*)(ws + 20971520);
  f16* Wob = (f16*)(ws + 23068672);
  f16* Qb  = (f16*)(ws + 25165824);
  f16* Kb  = (f16*)(ws + 41943040);
  f16* Vb  = (f16*)(ws + 58720256);
  f16* Ob  = Xb;

  const int nX = BATCH * SEQ * D_MODEL;
  const int nW = D_MODEL * D_MODEL;

  cvt_f32_f16<<<nX / 1024, 256, 0, stream>>>(x,  Xb,  nX);
  cvt_f32_f16<<<nW / 1024, 256, 0, stream>>>(wq, Wqb, nW);
  cvt_f32_f16<<<nW / 1024, 256, 0, stream>>>(wk, Wkb, nW);
  cvt_f32_f16<<<nW / 1024, 256, 0, stream>>>(wv, Wvb, nW);
  cvt_f32_f16<<<nW / 1024, 256, 0, stream>>>(wo, Wob, nW);

  // fused QKV projection: C[8192,3072] = X * Wqkv^T, split to Qb/Kb/Vb
  gemm_glds<1><<<dim3(24, 64), 256, 0, stream>>>(Xb, Wqb, Qb, Kb, Vb, D_MODEL);

  rope_kernel<<<(BATCH * SEQ * (D_MODEL / 2)) / 256, 256, 0, stream>>>(
      Qb, Kb, tokpos, BATCH * SEQ * (D_MODEL / 2));

  flash_attn<<<dim3(BATCH * NH, 32), 256, 0, stream>>>(Qb, Kb, Vb, Ob);

  gemm_glds<0><<<dim3(8, 64), 256, 0, stream>>>(Ob, Wob, out, nullptr, nullptr, D_MODEL);
}

// Round 6
// 269.323 us; speedup vs baseline: 2.5288x; 1.0568x over previous
//
#include <hip/hip_runtime.h>

// multihead self-attention: B=4 S=2048 D=1024 H=16 DK=64, causal, RoPE(theta=1e4)
// f16 pipeline: cvt | QKV = x*Wqkv^T (m97-pattern mfma gemm) | rope |
// transposed flash (S^T=K*Q^T swizzled-LDS, O^T=V^T*P^T reg-P) | out gemm (f32)

#define D_MODEL 1024
#define NH      16
#define DKH     64
#define SEQ     2048
#define BATCH   4
#define M_ROWS  (BATCH * SEQ)   // 8192
#define SCALE_LOG2 0.180336875461f   // (1/sqrt(64)) * log2(e); applied to Q pre-MFMA

typedef _Float16 f16;
typedef _Float16 f16x8 __attribute__((ext_vector_type(8)));
typedef _Float16 f16x4 __attribute__((ext_vector_type(4)));
typedef _Float16 f16x2 __attribute__((ext_vector_type(2)));
typedef __fp16   fp16x2n __attribute__((ext_vector_type(2)));   // cvt_pkrtz native type
typedef float    f32x4 __attribute__((ext_vector_type(4)));
typedef unsigned short u16;
typedef unsigned int   u32;

__device__ __forceinline__ void glds16(const void* g, void* l) {
  __builtin_amdgcn_global_load_lds((const __attribute__((address_space(1))) void*)g,
                                   (__attribute__((address_space(3))) void*)l, 16, 0, 0);
}
__device__ __forceinline__ u32 pk(float a, float b) {
  union { fp16x2n h; u32 u; } c; c.h = __builtin_amdgcn_cvt_pkrtz(a, b); return c.u;
}

// ---------------- f32 -> f16 convert (x) ----------------
__global__ void cvt_f32_f16(const float* __restrict__ in, f16* __restrict__ out, int n) {
  int i = (blockIdx.x * blockDim.x + threadIdx.x) * 4;
  if (i >= n) return;
  float4 v = *(const float4*)(in + i);
  uint2 o; o.x = pk(v.x, v.y); o.y = pk(v.z, v.w);
  *(uint2*)(out + i) = o;
}

// 4 weight tensors in one dispatch (grid.y selects)
__global__ void cvt_w4(const float* __restrict__ w0, const float* __restrict__ w1,
                       const float* __restrict__ w2, const float* __restrict__ w3,
                       f16* __restrict__ o0, f16* __restrict__ o1,
                       f16* __restrict__ o2, f16* __restrict__ o3, int n) {
  const float* src; f16* dst;
  switch (blockIdx.y) {
    case 0:  src = w0; dst = o0; break;
    case 1:  src = w1; dst = o1; break;
    case 2:  src = w2; dst = o2; break;
    default: src = w3; dst = o3; break;
  }
  int i = (blockIdx.x * blockDim.x + threadIdx.x) * 4;
  if (i >= n) return;
  float4 v = *(const float4*)(src + i);
  uint2 o; o.x = pk(v.x, v.y); o.y = pk(v.z, v.w);
  *(uint2*)(dst + i) = o;
}

// ---- GEMM C[M,N] = A[M,K]*W[N,K]^T, 128x128 tile, BK=64, m97 pattern:
// unpadded LDS [128][64], linear glds16 staging, plain b128 frag reads.
// MODE 0: f32 out. MODE 1: f16 out split Q/K/V by n0.
template<int MODE>
__global__ __launch_bounds__(256) void gemm_glds(const f16* __restrict__ A,
                                                 const f16* __restrict__ W,
                                                 void* __restrict__ C0,
                                                 void* __restrict__ C1,
                                                 void* __restrict__ C2,
                                                 int K) {
  __shared__ f16 As[128][64];
  __shared__ f16 Bs[128][64];
  const int tid  = threadIdx.x;
  const int m0   = blockIdx.y * 128;
  const int n0   = blockIdx.x * 128;
  const int wave = tid >> 6, lane = tid & 63;
  const int quad = lane >> 4, l16 = lane & 15;
  const int wm = (wave >> 1) * 64, wn = (wave & 1) * 64;

  f32x4 acc[4][4];
#pragma unroll
  for (int i = 0; i < 4; ++i)
#pragma unroll
    for (int j = 0; j < 4; ++j) acc[i][j] = (f32x4){0.f, 0.f, 0.f, 0.f};

  for (int k0 = 0; k0 < K; k0 += 64) {
    if (k0) __syncthreads();
#pragma unroll
    for (int i = 0; i < 4; ++i) {            // 4 rounds x 256 lanes x 16B per buffer
      int ci  = i * 256 + tid;
      int row = ci >> 3, ch = ci & 7;
      glds16(A + (size_t)(m0 + row) * K + k0 + ch * 8,
             (char*)&As[0][0] + (size_t)(i * 256 + (tid & 192)) * 16);
      glds16(W + (size_t)(n0 + row) * K + k0 + ch * 8,
             (char*)&Bs[0][0] + (size_t)(i * 256 + (tid & 192)) * 16);
    }
    __syncthreads();                         // drains glds vmcnt for all waves
#pragma unroll
    for (int kk = 0; kk < 64; kk += 32) {
      f16x8 af[4], bfr[4];
#pragma unroll
      for (int mi = 0; mi < 4; ++mi)
        af[mi] = *(const f16x8*)&As[wm + mi * 16 + l16][kk + quad * 8];
#pragma unroll
      for (int ni = 0; ni < 4; ++ni)
        bfr[ni] = *(const f16x8*)&Bs[wn + ni * 16 + l16][kk + quad * 8];
#pragma unroll
      for (int mi = 0; mi < 4; ++mi)
#pragma unroll
        for (int ni = 0; ni < 4; ++ni)
          acc[mi][ni] = __builtin_amdgcn_mfma_f32_16x16x32_f16(af[mi], bfr[ni], acc[mi][ni], 0, 0, 0);
    }
  }

  // epilogue: C layout col=lane&15, row=quad*4+reg
  if (MODE == 1) {
    f16* dst; int nb;
    if (n0 < 1024)      { dst = (f16*)C0; nb = n0; }
    else if (n0 < 2048) { dst = (f16*)C1; nb = n0 - 1024; }
    else                { dst = (f16*)C2; nb = n0 - 2048; }
#pragma unroll
    for (int mi = 0; mi < 4; ++mi)
#pragma unroll
      for (int ni = 0; ni < 4; ++ni)
#pragma unroll
        for (int r = 0; r < 4; ++r) {
          int row = m0 + wm + mi * 16 + quad * 4 + r;
          int col = nb + wn + ni * 16 + l16;
          dst[(size_t)row * 1024 + col] = (f16)acc[mi][ni][r];
        }
  } else {
    float* dst = (float*)C0;
#pragma unroll
    for (int mi = 0; mi < 4; ++mi)
#pragma unroll
      for (int ni = 0; ni < 4; ++ni)
#pragma unroll
        for (int r = 0; r < 4; ++r) {
          int row = m0 + wm + mi * 16 + quad * 4 + r;
          int col = n0 + wn + ni * 16 + l16;
          dst[(size_t)row * 1024 + col] = acc[mi][ni][r];
        }
  }
}

// ---------------- RoPE in-place on f16 Q and K ----------------
__global__ void rope_kernel(f16* __restrict__ Q, f16* __restrict__ Kb,
                            const int* __restrict__ pos, int npairs) {
  int p = blockIdx.x * blockDim.x + threadIdx.x;
  if (p >= npairs) return;
  int i = p & 31;
  int s = (p >> 9) & (SEQ - 1);
  float inv = __builtin_amdgcn_exp2f(-0.41524101186092029f * (float)i); // log2(1e4)/32
  float ang = (float)pos[s] * inv;
  float c = cosf(ang), sn = sinf(ang);

  union { u32 u; f16x2 h; } uq, uk;
  uq.u = *(u32*)(Q + 2 * (size_t)p);
  float qe = (float)uq.h[0], qo = (float)uq.h[1];
  *(u32*)(Q + 2 * (size_t)p) = pk(qe * c - qo * sn, qe * sn + qo * c);

  uk.u = *(u32*)(Kb + 2 * (size_t)p);
  float ke = (float)uk.h[0], ko = (float)uk.h[1];
  *(u32*)(Kb + 2 * (size_t)p) = pk(ke * c - ko * sn, ke * sn + ko * c);
}

// ---------------- transposed causal flash attention ----------------
// grid (B*H, 32); block 256 = 4 waves. Block owns 64 q-rows; KV-tiles of 128 keys,
// wave w owns keys [kt+32w, kt+32w+32). S^T = K*Q^T (16x16x32_f16) with Q pre-scaled
// by SCALE_LOG2 -> p = exp2(c) (offset-free: constant factor cancels in O/l) ->
// P^T register-resident as B-operand of 16x16x16_f16: O^T += V^T * P^T.
// Ks: unpadded [128][64] via glds16, xor-swizzled source chunks (conflict-lite b128).
// Vt: u32 [64][67] (stride 67: reads<=2-way, stores 2-way=free).
__global__ __launch_bounds__(256, 3) void flash_attn(const f16* __restrict__ Q,
                                                     const f16* __restrict__ Kg,
                                                     const f16* __restrict__ Vg,
                                                     f16* __restrict__ O) {
  __shared__ char smem[34560];
  f16*  KsL        = (f16*)smem;                  // [128][64] key x dk (swizzled), 16 KB
  u32   (*Vt)[67]  = (u32(*)[67])(smem + 16384);  // [64 dk][67 key-pair], 17152 B
  float (*Red)[66] = (float(*)[66])smem;          // reduction [64 dk][66], aliases Ks
  float (*Lbuf)[4] = (float(*)[4])(smem + 33536); // [64 q][quad]

  const int tid  = threadIdx.x;
  const int bh   = blockIdx.x;
  const int b    = bh >> 4, h = bh & 15;
  const int qblk = 31 - (int)blockIdx.y;          // longest first
  const int q0   = qblk * 64;
  const int wave = tid >> 6, lane = tid & 63;
  const int quad = lane >> 4, l16 = lane & 15;
  const int nkt  = (qblk + 2) >> 1;               // 128-key tiles covering q0+64 keys

  // Q B-frags (pre-scaled by SCALE_LOG2): B[k=dk][n=q] = Q[q=l16][dk=quad*8+j]
  f16x8 qf[4][2];
#pragma unroll
  for (int nt = 0; nt < 4; ++nt)
#pragma unroll
    for (int ks = 0; ks < 2; ++ks) {
      f16x8 qv = *(const f16x8*)(Q + ((size_t)(b * SEQ + q0 + nt * 16 + l16)) * D_MODEL
                                   + h * DKH + ks * 32 + quad * 8);
      qf[nt][ks] = qv * (f16)SCALE_LOG2;
    }

  f32x4 o[4][4];        // O^T partial: [dk-mtile][q-ntile], C layout dk=quad*4+r, q=l16
#pragma unroll
  for (int md = 0; md < 4; ++md)
#pragma unroll
    for (int nt = 0; nt < 4; ++nt) o[md][nt] = (f32x4){0.f, 0.f, 0.f, 0.f};
  float lacc[4] = {0.f, 0.f, 0.f, 0.f};

  const int kp = tid >> 3, dc = (tid & 7) * 8;    // V-transpose staging role

  for (int t = 0; t < nkt; ++t) {
    const int kt = t * 128;
    // V global loads early (keys 2kp,2kp+1 and 64+2kp,65+2kp; dk dc..dc+7)
    const f16* vb = Vg + ((size_t)(b * SEQ + kt + 2 * kp)) * D_MODEL + h * DKH + dc;
    uint4 v0 = *(const uint4*)vb;
    uint4 v1 = *(const uint4*)(vb + D_MODEL);
    uint4 v2 = *(const uint4*)(vb + 64 * D_MODEL);
    uint4 v3 = *(const uint4*)(vb + 65 * D_MODEL);

    if (t) __syncthreads();          // all waves done with prior Ks/Vt
    // K staging via glds16: LDS dest lane-linear, global chunk xor-swizzled
#pragma unroll
    for (int i = 0; i < 4; ++i) {
      int ci = i * 256 + tid;
      int row = ci >> 3, gc = (ci & 7) ^ (row & 7);
      glds16(Kg + ((size_t)(b * SEQ + kt + row)) * D_MODEL + h * DKH + gc * 8,
             smem + (size_t)(i * 256 + (tid & 192)) * 16);
    }
    {  // V transpose: key-pairs packed u32, [dk][kp], stride 67
      union { uint4 u; u16 s[8]; } a0, a1, a2, a3;
      a0.u = v0; a1.u = v1; a2.u = v2; a3.u = v3;
#pragma unroll
      for (int j = 0; j < 8; ++j) {
        Vt[dc + j][kp]      = (u32)a0.s[j] | ((u32)a1.s[j] << 16);
        Vt[dc + j][32 + kp] = (u32)a2.s[j] | ((u32)a3.s[j] << 16);
      }
    }
    __syncthreads();                 // also drains glds vmcnt

    // S^T = K_slice * Q^T (pre-scaled), exp2 -> P^T B-frags (registers only)
    f16x4 pb[2][4];
#pragma unroll
    for (int mt = 0; mt < 2; ++mt) {
      const int krow = wave * 32 + mt * 16 + l16;
      const int s0 = quad ^ (krow & 7);
      f16x8 ka0 = *(const f16x8*)(KsL + krow * 64 + s0 * 8);
      f16x8 ka1 = *(const f16x8*)(KsL + krow * 64 + (s0 ^ 4) * 8);
      const int keyb = kt + wave * 32 + mt * 16 + quad * 4;
#pragma unroll
      for (int nt = 0; nt < 4; ++nt) {
        f32x4 c = (f32x4){0.f, 0.f, 0.f, 0.f};
        c = __builtin_amdgcn_mfma_f32_16x16x32_f16(ka0, qf[nt][0], c, 0, 0, 0);
        c = __builtin_amdgcn_mfma_f32_16x16x32_f16(ka1, qf[nt][1], c, 0, 0, 0);
        const int q = q0 + nt * 16 + l16;
        float p0 = __builtin_amdgcn_exp2f(c[0]);
        float p1 = __builtin_amdgcn_exp2f(c[1]);
        float p2 = __builtin_amdgcn_exp2f(c[2]);
        float p3 = __builtin_amdgcn_exp2f(c[3]);
        if (t == nkt - 1) {          // causal mask (only last tile can clip)
          p0 = (keyb + 0 <= q) ? p0 : 0.f;
          p1 = (keyb + 1 <= q) ? p1 : 0.f;
          p2 = (keyb + 2 <= q) ? p2 : 0.f;
          p3 = (keyb + 3 <= q) ? p3 : 0.f;
        }
        lacc[nt] += (p0 + p1) + (p2 + p3);
        union { u32 w[2]; f16x4 v; } pp;
        pp.w[0] = pk(p0, p1); pp.w[1] = pk(p2, p3);
        pb[mt][nt] = pp.v;
      }
    }

    // O^T += V^T_slice * P^T  (16x16x16_f16, k = 16 keys per step)
#pragma unroll
    for (int md = 0; md < 4; ++md)
#pragma unroll
      for (int ks2 = 0; ks2 < 2; ++ks2) {
        const u32* vp = &Vt[md * 16 + l16][wave * 16 + ks2 * 8 + quad * 2];
        union { u32 x[2]; f16x4 v; } va;
        va.x[0] = vp[0]; va.x[1] = vp[1];
#pragma unroll
        for (int nt = 0; nt < 4; ++nt)
          o[md][nt] = __builtin_amdgcn_mfma_f32_16x16x16f16(va.v, pb[ks2][nt], o[md][nt], 0, 0, 0);
      }
  }

  __syncthreads();
  // cross-wave reduction of O^T and l (serial, once per block)
  for (int w = 0; w < 4; ++w) {
    if (wave == w) {
#pragma unroll
      for (int md = 0; md < 4; ++md)
#pragma unroll
        for (int nt = 0; nt < 4; ++nt)
#pragma unroll
          for (int r = 0; r < 4; ++r) {
            float* s = &Red[md * 16 + quad * 4 + r][nt * 16 + l16];
            if (w == 0) *s = o[md][nt][r]; else *s += o[md][nt][r];
          }
#pragma unroll
      for (int nt = 0; nt < 4; ++nt) {
        float* ls = &Lbuf[nt * 16 + l16][quad];
        if (w == 0) *ls = lacc[nt]; else *ls += lacc[nt];
      }
    }
    __syncthreads();
  }

  // normalize + store: thread -> (q, 16-dk chunk), 32B contiguous
  {
    const int q = tid & 63, dc4 = (tid >> 6) * 16;
    float lsum = Lbuf[q][0] + Lbuf[q][1] + Lbuf[q][2] + Lbuf[q][3];
    float linv = __builtin_amdgcn_rcpf(lsum);
    union { uint4 u[2]; u32 w[8]; } ov;
#pragma unroll
    for (int i = 0; i < 8; ++i)
      ov.w[i] = pk(Red[dc4 + 2 * i][q] * linv, Red[dc4 + 2 * i + 1][q] * linv);
    f16* op = O + ((size_t)(b * SEQ + q0 + q)) * D_MODEL + h * DKH + dc4;
    *(uint4*)op = ov.u[0];
    *(uint4*)(op + 8) = ov.u[1];
  }
}

// ---------------- launch ----------------
extern "C" void kernel_launch(void* const* d_in, const int* in_sizes, int n_in,
                              void* d_out, int out_size, void* d_ws, size_t ws_size,
                              hipStream_t stream) {
  const float* x      = (const float*)d_in[0];
  const int*   tokpos = (const int*)d_in[1];
  const float* wq     = (const float*)d_in[2];
  const float* wk     = (const float*)d_in[3];
  const float* wv     = (const float*)d_in[4];
  const float* wo     = (const float*)d_in[5];
  float* out = (float*)d_out;

  char* ws = (char*)d_ws;
  f16* Xb  = (f16*)(ws + 0);           // 16 MB (also Ob)
  f16* Wqb = (f16*)(ws + 16777216);    // Wq,Wk,Wv contiguous -> one [3072][1024]
  f16* Wkb = (f16*)(ws + 18874368);
  f16* Wvb = (f16*)(ws + 20971520);
  f16* Wob = (f16*)(ws + 23068672);
  f16* Qb  = (f16*)(ws + 25165824);
  f16* Kb  = (f16*)(ws + 41943040);
  f16* Vb  = (f16*)(ws + 58720256);
  f16* Ob  = Xb;

  const int nX = BATCH * SEQ * D_MODEL;
  const int nW = D_MODEL * D_MODEL;

  cvt_f32_f16<<<nX / 1024, 256, 0, stream>>>(x, Xb, nX);
  cvt_w4<<<dim3(nW / 1024, 4), 256, 0, stream>>>(wq, wk, wv, wo, Wqb, Wkb, Wvb, Wob, nW);

  // fused QKV projection: C[8192,3072] = X * Wqkv^T, split to Qb/Kb/Vb
  gemm_glds<1><<<dim3(24, 64), 256, 0, stream>>>(Xb, Wqb, Qb, Kb, Vb, D_MODEL);

  rope_kernel<<<(BATCH * SEQ * (D_MODEL / 2)) / 256, 256, 0, stream>>>(
      Qb, Kb, tokpos, BATCH * SEQ * (D_MODEL / 2));

  flash_attn<<<dim3(BATCH * NH, 32), 256, 0, stream>>>(Qb, Kb, Vb, Ob);

  gemm_glds<0><<<dim3(8, 64), 256, 0, stream>>>(Ob, Wob, out, nullptr, nullptr, D_MODEL);
}

// Round 7
// 255.126 us; speedup vs baseline: 2.6695x; 1.0556x over previous
//
#include <hip/hip_runtime.h>

// multihead self-attention: B=4 S=2048 D=1024 H=16 DK=64, causal, RoPE(theta=1e4)
// f16 pipeline, 4 dispatches:
//   cvt_all (x + 4 weights) | QKV = x*Wqkv^T with RoPE fused in epilogue |
//   transposed flash (S^T=K*Q^T swizzled-LDS, O^T=V^T*P^T reg-P) | out gemm (f32)

#define D_MODEL 1024
#define NH      16
#define DKH     64
#define SEQ     2048
#define BATCH   4
#define M_ROWS  (BATCH * SEQ)   // 8192
#define SCALE_LOG2 0.180336875461f   // (1/sqrt(64)) * log2(e); applied to Q pre-MFMA
#define ROPE_L2    0.41524101186092029f  // log2(1e4)/32

typedef _Float16 f16;
typedef _Float16 f16x8 __attribute__((ext_vector_type(8)));
typedef _Float16 f16x4 __attribute__((ext_vector_type(4)));
typedef _Float16 f16x2 __attribute__((ext_vector_type(2)));
typedef __fp16   fp16x2n __attribute__((ext_vector_type(2)));   // cvt_pkrtz native type
typedef float    f32x4 __attribute__((ext_vector_type(4)));
typedef unsigned short u16;
typedef unsigned int   u32;

__device__ __forceinline__ void glds16(const void* g, void* l) {
  __builtin_amdgcn_global_load_lds((const __attribute__((address_space(1))) void*)g,
                                   (__attribute__((address_space(3))) void*)l, 16, 0, 0);
}
__device__ __forceinline__ u32 pk(float a, float b) {
  union { fp16x2n h; u32 u; } c; c.h = __builtin_amdgcn_cvt_pkrtz(a, b); return c.u;
}

// ---------------- f32 -> f16 convert: x (8192 blocks) + 4 weights (1024 each) ----
__global__ void cvt_all(const float* __restrict__ x,
                        const float* __restrict__ w0, const float* __restrict__ w1,
                        const float* __restrict__ w2, const float* __restrict__ w3,
                        f16* __restrict__ xo, f16* __restrict__ o0, f16* __restrict__ o1,
                        f16* __restrict__ o2, f16* __restrict__ o3) {
  int blk = blockIdx.x;
  const float* src; f16* dst; int off;
  if (blk < 8192) { src = x; dst = xo; off = blk; }
  else {
    int t = blk - 8192; int w = t >> 10; off = t & 1023;
    switch (w) { case 0: src = w0; dst = o0; break;  case 1: src = w1; dst = o1; break;
                 case 2: src = w2; dst = o2; break;  default: src = w3; dst = o3; break; }
  }
  int i = (off * 256 + threadIdx.x) * 4;
  float4 v = *(const float4*)(src + i);
  uint2 o; o.x = pk(v.x, v.y); o.y = pk(v.z, v.w);
  *(uint2*)(dst + i) = o;
}

// ---- GEMM C[M,N] = A[M,K]*W[N,K]^T, 128x128 tile, BK=64, m97 pattern:
// unpadded LDS [128][64], linear glds16 staging, plain b128 frag reads.
// MODE 0: f32 out. MODE 1: f16 out split Q/K/V by n0, RoPE fused for Q,K:
//   pair (2i,2i+1) lives in adjacent lanes -> partner via shfl_xor(v,1);
//   out = v*cos + partner*(dk even ? -sin : +sin), rotation on f32 acc.
template<int MODE>
__global__ __launch_bounds__(256) void gemm_glds(const f16* __restrict__ A,
                                                 const f16* __restrict__ W,
                                                 void* __restrict__ C0,
                                                 void* __restrict__ C1,
                                                 void* __restrict__ C2,
                                                 const int* __restrict__ pos,
                                                 int K) {
  __shared__ f16 As[128][64];
  __shared__ f16 Bs[128][64];
  const int tid  = threadIdx.x;
  const int m0   = blockIdx.y * 128;
  const int n0   = blockIdx.x * 128;
  const int wave = tid >> 6, lane = tid & 63;
  const int quad = lane >> 4, l16 = lane & 15;
  const int wm = (wave >> 1) * 64, wn = (wave & 1) * 64;

  f32x4 acc[4][4];
#pragma unroll
  for (int i = 0; i < 4; ++i)
#pragma unroll
    for (int j = 0; j < 4; ++j) acc[i][j] = (f32x4){0.f, 0.f, 0.f, 0.f};

  for (int k0 = 0; k0 < K; k0 += 64) {
    if (k0) __syncthreads();
#pragma unroll
    for (int i = 0; i < 4; ++i) {            // 4 rounds x 256 lanes x 16B per buffer
      int ci  = i * 256 + tid;
      int row = ci >> 3, ch = ci & 7;
      glds16(A + (size_t)(m0 + row) * K + k0 + ch * 8,
             (char*)&As[0][0] + (size_t)(i * 256 + (tid & 192)) * 16);
      glds16(W + (size_t)(n0 + row) * K + k0 + ch * 8,
             (char*)&Bs[0][0] + (size_t)(i * 256 + (tid & 192)) * 16);
    }
    __syncthreads();                         // drains glds vmcnt for all waves
#pragma unroll
    for (int kk = 0; kk < 64; kk += 32) {
      f16x8 af[4], bfr[4];
#pragma unroll
      for (int mi = 0; mi < 4; ++mi)
        af[mi] = *(const f16x8*)&As[wm + mi * 16 + l16][kk + quad * 8];
#pragma unroll
      for (int ni = 0; ni < 4; ++ni)
        bfr[ni] = *(const f16x8*)&Bs[wn + ni * 16 + l16][kk + quad * 8];
#pragma unroll
      for (int mi = 0; mi < 4; ++mi)
#pragma unroll
        for (int ni = 0; ni < 4; ++ni)
          acc[mi][ni] = __builtin_amdgcn_mfma_f32_16x16x32_f16(af[mi], bfr[ni], acc[mi][ni], 0, 0, 0);
    }
  }

  // epilogue: C layout col=lane&15, row=quad*4+reg
  if (MODE == 1) {
    f16* dst; int nb;
    if (n0 < 1024)      { dst = (f16*)C0; nb = n0; }
    else if (n0 < 2048) { dst = (f16*)C1; nb = n0 - 1024; }
    else                { dst = (f16*)C2; nb = n0 - 2048; }
    if (n0 < 2048) {                         // Q or K: fused RoPE
      float invf[4], sgn[4];
#pragma unroll
      for (int ni = 0; ni < 4; ++ni) {
        int dk = (wn + ni * 16 + l16) & 63;
        invf[ni] = __builtin_amdgcn_exp2f(-ROPE_L2 * (float)(dk >> 1));
        sgn[ni]  = (dk & 1) ? 1.f : -1.f;
      }
#pragma unroll
      for (int mi = 0; mi < 4; ++mi)
#pragma unroll
        for (int r = 0; r < 4; ++r) {
          int row = m0 + wm + mi * 16 + quad * 4 + r;
          float ps = (float)pos[row & (SEQ - 1)];
#pragma unroll
          for (int ni = 0; ni < 4; ++ni) {
            float ang = ps * invf[ni];
            float c = __cosf(ang), sn = __sinf(ang);
            float v = acc[mi][ni][r];
            float p = __shfl_xor(v, 1);
            float ov = fmaf(p * sgn[ni], sn, v * c);
            int col = nb + wn + ni * 16 + l16;
            dst[(size_t)row * 1024 + col] = (f16)ov;
          }
        }
    } else {                                 // V: plain
#pragma unroll
      for (int mi = 0; mi < 4; ++mi)
#pragma unroll
        for (int ni = 0; ni < 4; ++ni)
#pragma unroll
          for (int r = 0; r < 4; ++r) {
            int row = m0 + wm + mi * 16 + quad * 4 + r;
            int col = nb + wn + ni * 16 + l16;
            dst[(size_t)row * 1024 + col] = (f16)acc[mi][ni][r];
          }
    }
  } else {
    float* dst = (float*)C0;
#pragma unroll
    for (int mi = 0; mi < 4; ++mi)
#pragma unroll
      for (int ni = 0; ni < 4; ++ni)
#pragma unroll
        for (int r = 0; r < 4; ++r) {
          int row = m0 + wm + mi * 16 + quad * 4 + r;
          int col = n0 + wn + ni * 16 + l16;
          dst[(size_t)row * 1024 + col] = acc[mi][ni][r];
        }
  }
}

// ---------------- transposed causal flash attention ----------------
// grid (B*H, 32); block 256 = 4 waves. Block owns 64 q-rows; KV-tiles of 128 keys,
// wave w owns keys [kt+32w, kt+32w+32). S^T = K*Q^T (16x16x32_f16) with Q pre-scaled
// by SCALE_LOG2 -> p = exp2(c) (offset-free: constant factor cancels in O/l) ->
// P^T register-resident as B-operand of 16x16x16_f16: O^T += V^T * P^T.
// Ks: unpadded [128][64] via glds16, xor-swizzled source chunks.
// Vt: u32 [64][67]. End reduction: wave-pairs into two Red buffers (3 barriers).
__global__ __launch_bounds__(256, 3) void flash_attn(const f16* __restrict__ Q,
                                                     const f16* __restrict__ Kg,
                                                     const f16* __restrict__ Vg,
                                                     f16* __restrict__ O) {
  __shared__ char smem[38400];
  f16*  KsL         = (f16*)smem;                   // [128][64] key x dk (swizzled), 16 KB
  u32   (*Vt)[67]   = (u32(*)[67])(smem + 16384);   // [64 dk][67 key-pair], 17152 B
  float (*Red0)[66] = (float(*)[66])smem;           // [64 dk][66 q] waves 0,1 (aliases Ks)
  float (*Red1)[66] = (float(*)[66])(smem + 16896); // waves 2,3 (aliases Vt)
  float (*Lb)[17]   = (float(*)[17])(smem + 33792); // [64 q][17], cols 0..15 = wave*4+quad

  const int tid  = threadIdx.x;
  const int bh   = blockIdx.x;
  const int b    = bh >> 4, h = bh & 15;
  const int qblk = 31 - (int)blockIdx.y;          // longest first
  const int q0   = qblk * 64;
  const int wave = tid >> 6, lane = tid & 63;
  const int quad = lane >> 4, l16 = lane & 15;
  const int nkt  = (qblk + 2) >> 1;               // 128-key tiles covering q0+64 keys

  // Q B-frags (pre-scaled by SCALE_LOG2): B[k=dk][n=q] = Q[q=l16][dk=quad*8+j]
  f16x8 qf[4][2];
#pragma unroll
  for (int nt = 0; nt < 4; ++nt)
#pragma unroll
    for (int ks = 0; ks < 2; ++ks) {
      f16x8 qv = *(const f16x8*)(Q + ((size_t)(b * SEQ + q0 + nt * 16 + l16)) * D_MODEL
                                   + h * DKH + ks * 32 + quad * 8);
      qf[nt][ks] = qv * (f16)SCALE_LOG2;
    }

  f32x4 o[4][4];        // O^T partial: [dk-mtile][q-ntile], C layout dk=quad*4+r, q=l16
#pragma unroll
  for (int md = 0; md < 4; ++md)
#pragma unroll
    for (int nt = 0; nt < 4; ++nt) o[md][nt] = (f32x4){0.f, 0.f, 0.f, 0.f};
  float lacc[4] = {0.f, 0.f, 0.f, 0.f};

  const int kp = tid >> 3, dc = (tid & 7) * 8;    // V-transpose staging role

  for (int t = 0; t < nkt; ++t) {
    const int kt = t * 128;
    // V global loads early (keys 2kp,2kp+1 and 64+2kp,65+2kp; dk dc..dc+7)
    const f16* vb = Vg + ((size_t)(b * SEQ + kt + 2 * kp)) * D_MODEL + h * DKH + dc;
    uint4 v0 = *(const uint4*)vb;
    uint4 v1 = *(const uint4*)(vb + D_MODEL);
    uint4 v2 = *(const uint4*)(vb + 64 * D_MODEL);
    uint4 v3 = *(const uint4*)(vb + 65 * D_MODEL);

    if (t) __syncthreads();          // all waves done with prior Ks/Vt
    // K staging via glds16: LDS dest lane-linear, global chunk xor-swizzled
#pragma unroll
    for (int i = 0; i < 4; ++i) {
      int ci = i * 256 + tid;
      int row = ci >> 3, gc = (ci & 7) ^ (row & 7);
      glds16(Kg + ((size_t)(b * SEQ + kt + row)) * D_MODEL + h * DKH + gc * 8,
             smem + (size_t)(i * 256 + (tid & 192)) * 16);
    }
    {  // V transpose: key-pairs packed u32, [dk][kp], stride 67
      union { uint4 u; u16 s[8]; } a0, a1, a2, a3;
      a0.u = v0; a1.u = v1; a2.u = v2; a3.u = v3;
#pragma unroll
      for (int j = 0; j < 8; ++j) {
        Vt[dc + j][kp]      = (u32)a0.s[j] | ((u32)a1.s[j] << 16);
        Vt[dc + j][32 + kp] = (u32)a2.s[j] | ((u32)a3.s[j] << 16);
      }
    }
    __syncthreads();                 // also drains glds vmcnt

    // S^T = K_slice * Q^T (pre-scaled), exp2 -> P^T B-frags (registers only)
    f16x4 pb[2][4];
#pragma unroll
    for (int mt = 0; mt < 2; ++mt) {
      const int krow = wave * 32 + mt * 16 + l16;
      const int s0 = quad ^ (krow & 7);
      f16x8 ka0 = *(const f16x8*)(KsL + krow * 64 + s0 * 8);
      f16x8 ka1 = *(const f16x8*)(KsL + krow * 64 + (s0 ^ 4) * 8);
      const int keyb = kt + wave * 32 + mt * 16 + quad * 4;
#pragma unroll
      for (int nt = 0; nt < 4; ++nt) {
        f32x4 c = (f32x4){0.f, 0.f, 0.f, 0.f};
        c = __builtin_amdgcn_mfma_f32_16x16x32_f16(ka0, qf[nt][0], c, 0, 0, 0);
        c = __builtin_amdgcn_mfma_f32_16x16x32_f16(ka1, qf[nt][1], c, 0, 0, 0);
        const int q = q0 + nt * 16 + l16;
        float p0 = __builtin_amdgcn_exp2f(c[0]);
        float p1 = __builtin_amdgcn_exp2f(c[1]);
        float p2 = __builtin_amdgcn_exp2f(c[2]);
        float p3 = __builtin_amdgcn_exp2f(c[3]);
        if (t == nkt - 1) {          // causal mask (only last tile can clip)
          p0 = (keyb + 0 <= q) ? p0 : 0.f;
          p1 = (keyb + 1 <= q) ? p1 : 0.f;
          p2 = (keyb + 2 <= q) ? p2 : 0.f;
          p3 = (keyb + 3 <= q) ? p3 : 0.f;
        }
        lacc[nt] += (p0 + p1) + (p2 + p3);
        union { u32 w[2]; f16x4 v; } pp;
        pp.w[0] = pk(p0, p1); pp.w[1] = pk(p2, p3);
        pb[mt][nt] = pp.v;
      }
    }

    // O^T += V^T_slice * P^T  (16x16x16_f16, k = 16 keys per step)
#pragma unroll
    for (int md = 0; md < 4; ++md)
#pragma unroll
      for (int ks2 = 0; ks2 < 2; ++ks2) {
        const u32* vp = &Vt[md * 16 + l16][wave * 16 + ks2 * 8 + quad * 2];
        union { u32 x[2]; f16x4 v; } va;
        va.x[0] = vp[0]; va.x[1] = vp[1];
#pragma unroll
        for (int nt = 0; nt < 4; ++nt)
          o[md][nt] = __builtin_amdgcn_mfma_f32_16x16x16f16(va.v, pb[ks2][nt], o[md][nt], 0, 0, 0);
      }
  }

  __syncthreads();
  // cross-wave reduction: wave-pairs {0,1}->Red0, {2,3}->Red1; L fully parallel
  {
    float (*Rw)[66] = (wave >= 2) ? Red1 : Red0;
    if ((wave & 1) == 0) {           // waves 0,2 initialize
#pragma unroll
      for (int md = 0; md < 4; ++md)
#pragma unroll
        for (int nt = 0; nt < 4; ++nt)
#pragma unroll
          for (int r = 0; r < 4; ++r)
            Rw[md * 16 + quad * 4 + r][nt * 16 + l16] = o[md][nt][r];
    }
#pragma unroll
    for (int nt = 0; nt < 4; ++nt)
      Lb[nt * 16 + l16][wave * 4 + quad] = lacc[nt];
    __syncthreads();
    if (wave & 1) {                  // waves 1,3 accumulate
#pragma unroll
      for (int md = 0; md < 4; ++md)
#pragma unroll
        for (int nt = 0; nt < 4; ++nt)
#pragma unroll
          for (int r = 0; r < 4; ++r)
            Rw[md * 16 + quad * 4 + r][nt * 16 + l16] += o[md][nt][r];
    }
    __syncthreads();
  }

  // normalize + store: thread -> (q, 16-dk chunk), 32B contiguous
  {
    const int q = tid & 63, dc4 = (tid >> 6) * 16;
    float lsum = 0.f;
#pragma unroll
    for (int j = 0; j < 16; ++j) lsum += Lb[q][j];
    float linv = __builtin_amdgcn_rcpf(lsum);
    union { uint4 u[2]; u32 w[8]; } ov;
#pragma unroll
    for (int i = 0; i < 8; ++i) {
      float f0 = Red0[dc4 + 2 * i][q]     + Red1[dc4 + 2 * i][q];
      float f1 = Red0[dc4 + 2 * i + 1][q] + Red1[dc4 + 2 * i + 1][q];
      ov.w[i] = pk(f0 * linv, f1 * linv);
    }
    f16* op = O + ((size_t)(b * SEQ + q0 + q)) * D_MODEL + h * DKH + dc4;
    *(uint4*)op = ov.u[0];
    *(uint4*)(op + 8) = ov.u[1];
  }
}

// ---------------- launch ----------------
extern "C" void kernel_launch(void* const* d_in, const int* in_sizes, int n_in,
                              void* d_out, int out_size, void* d_ws, size_t ws_size,
                              hipStream_t stream) {
  const float* x      = (const float*)d_in[0];
  const int*   tokpos = (const int*)d_in[1];
  const float* wq     = (const float*)d_in[2];
  const float* wk     = (const float*)d_in[3];
  const float* wv     = (const float*)d_in[4];
  const float* wo     = (const float*)d_in[5];
  float* out = (float*)d_out;

  char* ws = (char*)d_ws;
  f16* Xb  = (f16*)(ws + 0);           // 16 MB (also Ob)
  f16* Wqb = (f16*)(ws + 16777216);    // Wq,Wk,Wv contiguous -> one [3072][1024]
  f16* Wkb = (f16*)(ws + 18874368);
  f16* Wvb = (f16*)(ws + 20971520);
  f16* Wob = (f16*)(ws + 23068672);
  f16* Qb  = (f16*)(ws + 25165824);
  f16* Kb  = (f16*)(ws + 41943040);
  f16* Vb  = (f16*)(ws + 58720256);
  f16* Ob  = Xb;

  cvt_all<<<12288, 256, 0, stream>>>(x, wq, wk, wv, wo, Xb, Wqb, Wkb, Wvb, Wob);

  // fused QKV projection + RoPE: C[8192,3072] = X * Wqkv^T, split to Qb/Kb/Vb
  gemm_glds<1><<<dim3(24, 64), 256, 0, stream>>>(Xb, Wqb, Qb, Kb, Vb, tokpos, D_MODEL);

  flash_attn<<<dim3(BATCH * NH, 32), 256, 0, stream>>>(Qb, Kb, Vb, Ob);

  gemm_glds<0><<<dim3(8, 64), 256, 0, stream>>>(Ob, Wob, out, nullptr, nullptr, nullptr, D_MODEL);
}